// Round 16
// baseline (136.105 us; speedup 1.0000x reference)
//
#include <hip/hip_runtime.h>
#include <hip/hip_bf16.h>
#include <stdint.h>
#include <math.h>

#define DI __device__ __forceinline__

typedef __bf16 bf16x8 __attribute__((ext_vector_type(8)));
typedef float f32x4 __attribute__((ext_vector_type(4)));
typedef unsigned short ushortx8 __attribute__((ext_vector_type(8)));

// fp32 -> bf16 round-to-nearest-even (scalar path)
DI unsigned short f2bf(float f) {
    unsigned int u = __builtin_bit_cast(unsigned int, f);
    u += 0x7fffu + ((u >> 16) & 1u);
    return (unsigned short)(u >> 16);
}

// packed fp32x2 -> bf16x2 (1 VALU op). lo -> bits 0-15, hi -> bits 16-31.
DI unsigned int cvt_pk_bf16(float lo, float hi) {
    unsigned int r;
    asm("v_cvt_pk_bf16_f32 %0, %1, %2" : "=v"(r) : "v"(lo), "v"(hi));
    return r;
}

DI f32x4 mfma_16x16x32_bf16(bf16x8 a, bf16x8 b, f32x4 c) {
    return __builtin_amdgcn_mfma_f32_16x16x32_bf16(a, b, c, 0, 0, 0);
}

// async global->LDS, 16B per lane. LDS dest: wave-uniform base + lane*16.
DI void gload16(const unsigned short* g, unsigned short* l) {
    __builtin_amdgcn_global_load_lds(
        (const __attribute__((address_space(1))) void*)g,
        (__attribute__((address_space(3))) void*)l, 16, 0, 0);
}

// ---------------------------------------------------------------------------
// k_prep: fused prep (proven). Blocks 0..3071: fp32->bf16 cvt of Q/K/V.
// Blocks 3072..4095: W -> Wt bf16 transpose (4 matrices, 64x64 tiles).
// ---------------------------------------------------------------------------
__global__ __launch_bounds__(256) void k_prep(
    const float* __restrict__ Q, const float* __restrict__ K, const float* __restrict__ V,
    unsigned short* __restrict__ qc, unsigned short* __restrict__ kc, unsigned short* __restrict__ vc,
    const float* __restrict__ w0, const float* __restrict__ w1,
    const float* __restrict__ w2, const float* __restrict__ w3,
    unsigned short* __restrict__ o0, unsigned short* __restrict__ o1,
    unsigned short* __restrict__ o2, unsigned short* __restrict__ o3)
{
    constexpr int N = 1024;
    __shared__ unsigned short L[64 * 64];
    const int bx = blockIdx.x;
    const int tid = threadIdx.x;

    if (bx < 3072) {
        const int z = bx >> 10;
        const int ib = bx & 1023;
        const float* s = z == 0 ? Q : z == 1 ? K : V;
        unsigned short* d = z == 0 ? qc : z == 1 ? kc : vc;
        const int i0 = ib * 256 + tid;
        #pragma unroll
        for (int it = 0; it < 4; ++it) {
            const int i = i0 + it * 262144;
            const float4 v = reinterpret_cast<const float4*>(s)[i];
            uint2 pk;
            pk.x = cvt_pk_bf16(v.x, v.y);
            pk.y = cvt_pk_bf16(v.z, v.w);
            reinterpret_cast<uint2*>(d)[i] = pk;
        }
    } else {
        const int r4 = bx - 3072;
        const int z = r4 >> 8;
        const int tile = r4 & 255;
        const float* W = z == 0 ? w0 : z == 1 ? w1 : z == 2 ? w2 : w3;
        unsigned short* O = z == 0 ? o0 : z == 1 ? o1 : z == 2 ? o2 : o3;
        const int k0 = (tile >> 4) * 64, n0 = (tile & 15) * 64;

        const int r = tid >> 2, cbase = (tid & 3) * 16;
        #pragma unroll
        for (int i = 0; i < 4; ++i) {
            const int c = cbase + i * 4;
            const float4 v = *reinterpret_cast<const float4*>(&W[(size_t)(k0 + r) * N + n0 + c]);
            uint2 pk;
            pk.x = cvt_pk_bf16(v.x, v.y);
            pk.y = cvt_pk_bf16(v.z, v.w);
            const int byte = r * 128 + ((c * 2) ^ ((r & 7) << 4));
            *reinterpret_cast<uint2*>(reinterpret_cast<char*>(L) + byte) = pk;
        }
        __syncthreads();

        const int n = tid >> 2, kc2 = (tid & 3) * 16;
        ushortx8 v0, v1;
        #pragma unroll
        for (int j = 0; j < 8; ++j) {
            const int ka = kc2 + j, kb2 = kc2 + 8 + j;
            v0[j] = *reinterpret_cast<const unsigned short*>(
                reinterpret_cast<const char*>(L) + ka * 128 + ((n * 2) ^ ((ka & 7) << 4)));
            v1[j] = *reinterpret_cast<const unsigned short*>(
                reinterpret_cast<const char*>(L) + kb2 * 128 + ((n * 2) ^ ((kb2 & 7) << 4)));
        }
        unsigned short* op = &O[(size_t)(n0 + n) * N + k0 + kc2];
        *reinterpret_cast<ushortx8*>(op) = v0;
        *reinterpret_cast<ushortx8*>(op + 8) = v1;
    }
}

// ---------------------------------------------------------------------------
// bf16 GEMM, BK=64, both-sides swizzle (proven; conflicts = 0), now launched
// on a 1D grid with chunked XCD swizzle so blocks sharing B-panels co-locate
// on one XCD's L2. BN=128 (QKV) or 64 (out-proj).
// ---------------------------------------------------------------------------
template <int MODE, int BN>
__global__ __launch_bounds__(256) void k_gemm_bf16(
    const unsigned short* __restrict__ A0, const unsigned short* __restrict__ A1,
    const unsigned short* __restrict__ A2,
    const unsigned short* __restrict__ B0, const unsigned short* __restrict__ B1,
    const unsigned short* __restrict__ B2,
    const float* __restrict__ bias0, const float* __restrict__ bias1,
    const float* __restrict__ bias2,
    void* C0, void* C1, void* C2)
{
    constexpr int K = 1024, N = 1024;
    constexpr int NJ = BN / 32;
    constexpr int NBY = (BN == 128) ? 8 : 16;
    constexpr int NBZ = (MODE == 1) ? 3 : 1;
    constexpr int NB = 32 * NBY * NBZ;
    constexpr int CH = NB / 8;

    // chunked XCD swizzle: consecutive-G chunk of CH blocks per XCD
    const int L = blockIdx.x;
    const int G = (L & 7) * CH + (L >> 3);
    const int bx = G & 31;
    const int rest = G >> 5;
    const int by = rest % NBY;
    const int z = (MODE == 1) ? (rest / NBY) : 0;

    const unsigned short* A  = z == 0 ? A0 : z == 1 ? A1 : A2;
    const unsigned short* Bt = z == 0 ? B0 : z == 1 ? B1 : B2;
    const float* bias        = z == 0 ? bias0 : z == 1 ? bias1 : bias2;
    void* C                  = z == 0 ? C0 : z == 1 ? C1 : C2;

    __shared__ unsigned short As[128 * 64];      // [row][k] 128-B rows
    __shared__ unsigned short Bs[BN * 64];

    const int tid  = threadIdx.x;
    const int lane = tid & 63;
    const int w    = tid >> 6;
    const int wr   = w >> 1, wc = w & 1;
    const int fr   = lane & 15, kg = lane >> 4;
    const int m0   = bx * 128, n0 = by * BN;

    const int srow8 = lane >> 3;
    const int sswz  = ((lane & 7) ^ (lane >> 3)) * 8;

    f32x4 acc[4][NJ] = {};

    for (int t = 0; t < K / 64; ++t) {
        const int k0 = t * 64;
        #pragma unroll
        for (int it = 0; it < 4; ++it) {
            const int c = w * 4 + it;
            gload16(&A[(size_t)(m0 + c * 8 + srow8) * K + k0 + sswz], &As[c * 512]);
            if (BN == 128)
                gload16(&Bt[(size_t)(n0 + c * 8 + srow8) * K + k0 + sswz], &Bs[c * 512]);
        }
        if (BN == 64) {
            #pragma unroll
            for (int it = 0; it < 2; ++it) {
                const int c = w * 2 + it;
                gload16(&Bt[(size_t)(n0 + c * 8 + srow8) * K + k0 + sswz], &Bs[c * 512]);
            }
        }
        __syncthreads();

        const int rsw = (fr & 7) << 4;
        #pragma unroll
        for (int kh = 0; kh < 2; ++kh) {
            bf16x8 af[4], bfj[NJ];
            #pragma unroll
            for (int i = 0; i < 4; ++i)
                af[i] = *reinterpret_cast<const bf16x8*>(
                    reinterpret_cast<const char*>(As) +
                    (wr * 64 + i * 16 + fr) * 128 + ((kh * 64 + kg * 16) ^ rsw));
            #pragma unroll
            for (int j = 0; j < NJ; ++j)
                bfj[j] = *reinterpret_cast<const bf16x8*>(
                    reinterpret_cast<const char*>(Bs) +
                    (wc * (BN / 2) + j * 16 + fr) * 128 + ((kh * 64 + kg * 16) ^ rsw));
            #pragma unroll
            for (int i = 0; i < 4; ++i)
                #pragma unroll
                for (int j = 0; j < NJ; ++j)
                    acc[i][j] = mfma_16x16x32_bf16(af[i], bfj[j], acc[i][j]);
        }
        __syncthreads();
    }

    if (MODE == 1 && z == 2) {
        unsigned short* vt = reinterpret_cast<unsigned short*>(C);
        #pragma unroll
        for (int i = 0; i < 4; ++i) {
            const int m = m0 + wr * 64 + i * 16 + kg * 4;
            const int bb = m >> 11, s = m & 2047;
            #pragma unroll
            for (int j = 0; j < NJ; ++j) {
                const int n = n0 + wc * (BN / 2) + j * 16 + fr;
                const float bv = bias[n];
                uint2 pk;
                pk.x = cvt_pk_bf16(acc[i][j][0] + bv, acc[i][j][1] + bv);
                pk.y = cvt_pk_bf16(acc[i][j][2] + bv, acc[i][j][3] + bv);
                *reinterpret_cast<uint2*>(&vt[((size_t)(bb * 1024 + n)) * 2048 + s]) = pk;
            }
        }
    } else if (MODE == 1) {
        const float sc = (z == 0) ? 0.125f * 1.44269504088896340736f : 1.0f;
        unsigned short* Cb = reinterpret_cast<unsigned short*>(C);
        #pragma unroll
        for (int i = 0; i < 4; ++i) {
            const int m = m0 + wr * 64 + i * 16 + kg * 4;
            #pragma unroll
            for (int j = 0; j < NJ; ++j) {
                const int n = n0 + wc * (BN / 2) + j * 16 + fr;
                const float bv = bias[n];
                const unsigned int p0 = cvt_pk_bf16((acc[i][j][0] + bv) * sc, (acc[i][j][1] + bv) * sc);
                const unsigned int p1 = cvt_pk_bf16((acc[i][j][2] + bv) * sc, (acc[i][j][3] + bv) * sc);
                Cb[(size_t)(m + 0) * N + n] = (unsigned short)p0;
                Cb[(size_t)(m + 1) * N + n] = (unsigned short)(p0 >> 16);
                Cb[(size_t)(m + 2) * N + n] = (unsigned short)p1;
                Cb[(size_t)(m + 3) * N + n] = (unsigned short)(p1 >> 16);
            }
        }
    } else {
        float* Cf = reinterpret_cast<float*>(C);
        #pragma unroll
        for (int i = 0; i < 4; ++i) {
            const int m = m0 + wr * 64 + i * 16 + kg * 4;
            #pragma unroll
            for (int j = 0; j < NJ; ++j) {
                const int n = n0 + wc * (BN / 2) + j * 16 + fr;
                const float bv = bias[n];
                #pragma unroll
                for (int r = 0; r < 4; ++r)
                    Cf[(size_t)(m + r) * N + n] = acc[i][j][r] + bv;
            }
        }
    }
}

// ---------------------------------------------------------------------------
// V tail suffix sums (unchanged).
// ---------------------------------------------------------------------------
__global__ __launch_bounds__(256) void k_vtail(
    const unsigned short* __restrict__ vt, float* __restrict__ vtail)
{
    const int row = blockIdx.x * 4 + (threadIdx.x >> 6);
    const int l = threadIdx.x & 63;
    const unsigned short* p = &vt[(size_t)row * 2048 + l * 32];
    float s = 0.f;
    #pragma unroll
    for (int i = 0; i < 4; ++i) {
        ushortx8 v = *reinterpret_cast<const ushortx8*>(&p[i * 8]);
        #pragma unroll
        for (int e = 0; e < 8; ++e)
            s += __builtin_bit_cast(float, (unsigned int)v[e] << 16);
    }
    #pragma unroll
    for (int off = 1; off < 64; off <<= 1) {
        const float t = __shfl_down(s, off, 64);
        s += (l + off < 64) ? t : 0.f;
    }
    float tv = __shfl(s, (2 * l + 2) & 63, 64);
    if (l == 31) tv = 0.f;
    if (l < 32) vtail[(size_t)row * 32 + l] = tv;
}

// ---------------------------------------------------------------------------
// Attention v9: KVBLK=128 (halves tiles/barriers; pair (31-p,p) is a uniform
// 17 tiles for every p). K LDS [128][128B] swz (row&7)<<4; V^T LDS [64][256B]
// swz (row&15)<<4; P [16][256B]/wave. Diagonal 128-tile: keys past the causal
// boundary (>= qoff+64 local) are the analytic-tail's territory -> e = 0
// in-tile (vtail covers them); masked-but-in-range keys -> e = 1.0 (exp(-1e-8)).
// ---------------------------------------------------------------------------
template <bool MASK>
DI void attn_tile(const unsigned char* KsB, const unsigned char* VtsB,
                  unsigned char* PB, bf16x8 qf0, bf16x8 qf1,
                  f32x4 (&o)[4], float& lsum, int qoff, int w, int fr, int kg)
{
    const int swk = (fr & 7) << 4;
    const int swp = (fr & 15) << 4;
    #pragma unroll
    for (int j = 0; j < 8; ++j) {
        const int row = j * 16 + fr;             // key row 0..127
        const bf16x8 kf0 = *reinterpret_cast<const bf16x8*>(KsB + row * 128 + ((kg * 16) ^ swk));
        const bf16x8 kf1 = *reinterpret_cast<const bf16x8*>(KsB + row * 128 + ((64 + kg * 16) ^ swk));
        f32x4 s = {0.f, 0.f, 0.f, 0.f};
        __builtin_amdgcn_s_setprio(1);
        s = mfma_16x16x32_bf16(kf0, qf0, s);     // swapped: A=K rows (keys), B=Q
        s = mfma_16x16x32_bf16(kf1, qf1, s);
        __builtin_amdgcn_s_setprio(0);
        float p[4];
        #pragma unroll
        for (int r = 0; r < 4; ++r) {
            float e = exp2f(s[r]);               // q pre-scaled by log2e
            if (MASK) {
                const int kl = j * 16 + kg * 4 + r;
                if (kl > qoff + w * 16 + fr) e = 1.0f;   // exp(-1e-8) == 1.0f
                if (kl >= qoff + 64)         e = 0.0f;   // analytic-tail territory
            }
            p[r] = e;
            lsum += e;
        }
        uint2 pk;
        pk.x = cvt_pk_bf16(p[0], p[1]);
        pk.y = cvt_pk_bf16(p[2], p[3]);
        *reinterpret_cast<uint2*>(PB + fr * 256 + ((j * 32 + kg * 8) ^ swp)) = pk;
    }
    __builtin_amdgcn_s_setprio(1);
    #pragma unroll
    for (int kk = 0; kk < 4; ++kk) {
        const bf16x8 pf = *reinterpret_cast<const bf16x8*>(PB + fr * 256 + ((kk * 64 + kg * 16) ^ swp));
        #pragma unroll
        for (int n = 0; n < 4; ++n) {
            const int vr = n * 16 + fr;
            const bf16x8 vf = *reinterpret_cast<const bf16x8*>(VtsB + vr * 256 + ((kk * 64 + kg * 16) ^ ((vr & 15) << 4)));
            o[n] = mfma_16x16x32_bf16(pf, vf, o[n]);
        }
    }
    __builtin_amdgcn_s_setprio(0);
}

DI void attn_sweep(int qt,
                   const unsigned short* __restrict__ qp,
                   const unsigned short* __restrict__ kp,
                   const unsigned short* __restrict__ vt,
                   const float* __restrict__ vtail,
                   unsigned short* __restrict__ ctx,
                   unsigned char (*KsB)[128 * 128], unsigned char (*VtsB)[64 * 256],
                   unsigned char* PB, size_t baseQ, size_t baseV, int b, int h,
                   int tid, int w, int fr, int kg)
{
    constexpr int S = 2048, D = 1024;
    const int q0 = qt * 64 + w * 16;

    bf16x8 qf0, qf1;
    {
        const size_t roff = baseQ + (size_t)(q0 + fr) * D;
        qf0 = *reinterpret_cast<const bf16x8*>(&qp[roff + kg * 8]);
        qf1 = *reinterpret_cast<const bf16x8*>(&qp[roff + 32 + kg * 8]);
    }

    f32x4 o[4] = {};
    float lsum = 0.f;
    const int NT2 = (qt >> 1) + 1;      // 128-key tiles
    const int qoff = (qt & 1) << 6;     // q-block offset within diagonal tile

    // staging indices: K rows 128B wide (8 thr/row), V rows 256B (16 thr/row)
    const int krow = tid >> 3, ke = (tid & 7) * 8,  ksl = (tid & 7) * 16;
    const int vrow = tid >> 4, ve = (tid & 15) * 8, vsl = (tid & 15) * 16;

    // prologue: stage tile 0 into buffer 0
    #pragma unroll
    for (int i = 0; i < 4; ++i) {
        const int r = krow + 32 * i;
        *reinterpret_cast<ushortx8*>(KsB[0] + r * 128 + (ksl ^ ((r & 7) << 4))) =
            *reinterpret_cast<const ushortx8*>(&kp[baseQ + (size_t)r * D + ke]);
        const int rv = vrow + 16 * i;
        *reinterpret_cast<ushortx8*>(VtsB[0] + rv * 256 + (vsl ^ ((rv & 15) << 4))) =
            *reinterpret_cast<const ushortx8*>(&vt[baseV + (size_t)rv * S + ve]);
    }
    __syncthreads();

    for (int t = 0; t < NT2; ++t) {
        const int cur = t & 1;
        const bool more = (t + 1 < NT2);
        ushortx8 nk[4], nv[4];
        if (more) {     // T14: issue next-tile loads before compute
            const int kb = (t + 1) * 128;
            #pragma unroll
            for (int i = 0; i < 4; ++i) {
                nk[i] = *reinterpret_cast<const ushortx8*>(
                    &kp[baseQ + (size_t)(kb + krow + 32 * i) * D + ke]);
                nv[i] = *reinterpret_cast<const ushortx8*>(
                    &vt[baseV + (size_t)(vrow + 16 * i) * S + kb + ve]);
            }
        }
        if (t == NT2 - 1)
            attn_tile<true>(KsB[cur], VtsB[cur], PB, qf0, qf1, o, lsum, qoff, w, fr, kg);
        else
            attn_tile<false>(KsB[cur], VtsB[cur], PB, qf0, qf1, o, lsum, 0, w, fr, kg);
        if (more) {
            const int nxt = cur ^ 1;
            #pragma unroll
            for (int i = 0; i < 4; ++i) {
                const int r = krow + 32 * i;
                *reinterpret_cast<ushortx8*>(KsB[nxt] + r * 128 + (ksl ^ ((r & 7) << 4))) = nk[i];
                const int rv = vrow + 16 * i;
                *reinterpret_cast<ushortx8*>(VtsB[nxt] + rv * 256 + (vsl ^ ((rv & 15) << 4))) = nv[i];
            }
        }
        __syncthreads();
    }

    // full row sums: combine the 4 key-groups, add analytic tail count
    lsum += __shfl_xor(lsum, 16, 64);
    lsum += __shfl_xor(lsum, 32, 64);
    lsum += (float)(S - (qt + 1) * 64);

    float rlq[4];
    #pragma unroll
    for (int r = 0; r < 4; ++r) rlq[r] = 1.0f / __shfl(lsum, kg * 4 + r, 64);

    float tl[4];
    #pragma unroll
    for (int n = 0; n < 4; ++n)
        tl[n] = vtail[((size_t)(b * 1024) + h * 64 + n * 16 + fr) * 32 + qt];

    #pragma unroll
    for (int n = 0; n < 4; ++n)
        #pragma unroll
        for (int r = 0; r < 4; ++r) {
            const int qrow = q0 + kg * 4 + r;
            ctx[baseQ + (size_t)qrow * D + n * 16 + fr] = f2bf((o[n][r] + tl[n]) * rlq[r]);
        }
}

__global__ __launch_bounds__(256, 2) void k_attn(
    const unsigned short* __restrict__ qp,
    const unsigned short* __restrict__ kp,
    const unsigned short* __restrict__ vt,
    const float* __restrict__ vtail,
    unsigned short* __restrict__ ctx)
{
    constexpr int S = 2048, D = 1024;
    // T1 chunked XCD swizzle (bijective, 512 = 8*64)
    const int L = blockIdx.x;
    const int G = (L & 7) * 64 + (L >> 3);
    const int p = G & 15;
    const int h = (G >> 4) & 15;
    const int b = G >> 8;

    __shared__ alignas(16) unsigned char KsB[2][128 * 128];   // dbuf K, swz (r&7)<<4
    __shared__ alignas(16) unsigned char VtsB[2][64 * 256];   // dbuf V^T, swz (r&15)<<4
    __shared__ alignas(16) unsigned char PlsB[4 * 16 * 256];  // per-wave P

    const int tid  = threadIdx.x;
    const int lane = tid & 63, w = tid >> 6;
    const int fr   = lane & 15, kg = lane >> 4;
    unsigned char* PB = PlsB + w * 4096;

    const size_t baseQ = ((size_t)b * S) * D + (size_t)h * 64;
    const size_t baseV = ((size_t)b * D + (size_t)h * 64) * S;

    // pair (31-p, p): 128-key tiles = ceil((32-p)/2) + ceil((p+1)/2) = 17, uniform
    attn_sweep(31 - p, qp, kp, vt, vtail, ctx, KsB, VtsB, PB,
               baseQ, baseV, b, h, tid, w, fr, kg);
    attn_sweep(p, qp, kp, vt, vtail, ctx, KsB, VtsB, PB,
               baseQ, baseV, b, h, tid, w, fr, kg);
}

// ---------------------------------------------------------------------------
extern "C" void kernel_launch(void* const* d_in, const int* in_sizes, int n_in,
                              void* d_out, int out_size, void* d_ws, size_t ws_size,
                              hipStream_t stream) {
    constexpr int B = 2, S = 2048, D = 1024;
    constexpr int M = B * S;                 // 4096
    constexpr size_t MD = (size_t)M * D;     // 4M elements

    const float* Q  = (const float*)d_in[0];
    const float* K  = (const float*)d_in[1];
    const float* V  = (const float*)d_in[2];
    const float* Wq = (const float*)d_in[4];
    const float* bq = (const float*)d_in[5];
    const float* Wk = (const float*)d_in[6];
    const float* bk = (const float*)d_in[7];
    const float* Wv = (const float*)d_in[8];
    const float* bv = (const float*)d_in[9];
    const float* Wo = (const float*)d_in[10];
    const float* bo = (const float*)d_in[11];

    // d_out (16 MiB, dead until final GEMM): qc (8 MiB) + kc (8 MiB)
    unsigned short* qc = (unsigned short*)d_out;
    unsigned short* kc = qc + MD;
    // d_ws (40 MiB): qb, kb, vtg, vc/ctx (8 MiB each) + Wto/Wtq/Wtk/Wtv (2 MiB each)
    char* ws = (char*)d_ws;
    unsigned short* qb  = (unsigned short*)(ws);
    unsigned short* kb  = (unsigned short*)(ws + (8u << 20));
    unsigned short* vtg = (unsigned short*)(ws + (16u << 20));
    unsigned short* vc  = (unsigned short*)(ws + (24u << 20));
    unsigned short* Wto = (unsigned short*)(ws + (32u << 20));
    unsigned short* Wtq = (unsigned short*)(ws + (34u << 20));
    unsigned short* Wtk = (unsigned short*)(ws + (36u << 20));
    unsigned short* Wtv = (unsigned short*)(ws + (38u << 20));
    unsigned short* ctx = vc;                       // aliases vc (dead by then)
    float* vtail        = (float*)Wtq;              // aliases Wtq (dead by then)

    dim3 blk(256);
    k_prep<<<dim3(4096), blk, 0, stream>>>(
        Q, K, V, qc, kc, vc, Wq, Wk, Wv, Wo, Wtq, Wtk, Wtv, Wto);
    k_gemm_bf16<1, 128><<<dim3(768), blk, 0, stream>>>(
        qc, kc, vc, Wtq, Wtk, Wtv, bq, bk, bv, qb, kb, vtg);
    k_vtail<<<dim3((B * D) / 4), blk, 0, stream>>>(vtg, vtail);
    k_attn<<<dim3(512), blk, 0, stream>>>(qb, kb, vtg, vtail, ctx);
    k_gemm_bf16<0, 64><<<dim3(512), blk, 0, stream>>>(
        ctx, ctx, ctx, Wto, Wto, Wto, bo, bo, bo, d_out, d_out, d_out);
}

// Round 17
// 123.574 us; speedup vs baseline: 1.1014x; 1.1014x over previous
//
#include <hip/hip_runtime.h>
#include <hip/hip_bf16.h>
#include <stdint.h>
#include <math.h>

#define DI __device__ __forceinline__

typedef __bf16 bf16x8 __attribute__((ext_vector_type(8)));
typedef float f32x4 __attribute__((ext_vector_type(4)));
typedef unsigned short ushortx8 __attribute__((ext_vector_type(8)));

// fp32 -> bf16 round-to-nearest-even (scalar path)
DI unsigned short f2bf(float f) {
    unsigned int u = __builtin_bit_cast(unsigned int, f);
    u += 0x7fffu + ((u >> 16) & 1u);
    return (unsigned short)(u >> 16);
}

// packed fp32x2 -> bf16x2 (1 VALU op). lo -> bits 0-15, hi -> bits 16-31.
DI unsigned int cvt_pk_bf16(float lo, float hi) {
    unsigned int r;
    asm("v_cvt_pk_bf16_f32 %0, %1, %2" : "=v"(r) : "v"(lo), "v"(hi));
    return r;
}

DI f32x4 mfma_16x16x32_bf16(bf16x8 a, bf16x8 b, f32x4 c) {
    return __builtin_amdgcn_mfma_f32_16x16x32_bf16(a, b, c, 0, 0, 0);
}

// async global->LDS, 16B per lane. LDS dest: wave-uniform base + lane*16.
DI void gload16(const unsigned short* g, unsigned short* l) {
    __builtin_amdgcn_global_load_lds(
        (const __attribute__((address_space(1))) void*)g,
        (__attribute__((address_space(3))) void*)l, 16, 0, 0);
}

// ---------------------------------------------------------------------------
// k_prep: fused prep (round-14 proven). Blocks 0..3071: fp32->bf16 cvt of
// Q/K/V. Blocks 3072..4095: W -> Wt bf16 transpose (4 matrices, 64x64 tiles).
// ---------------------------------------------------------------------------
__global__ __launch_bounds__(256) void k_prep(
    const float* __restrict__ Q, const float* __restrict__ K, const float* __restrict__ V,
    unsigned short* __restrict__ qc, unsigned short* __restrict__ kc, unsigned short* __restrict__ vc,
    const float* __restrict__ w0, const float* __restrict__ w1,
    const float* __restrict__ w2, const float* __restrict__ w3,
    unsigned short* __restrict__ o0, unsigned short* __restrict__ o1,
    unsigned short* __restrict__ o2, unsigned short* __restrict__ o3)
{
    constexpr int N = 1024;
    __shared__ unsigned short L[64 * 64];
    const int bx = blockIdx.x;
    const int tid = threadIdx.x;

    if (bx < 3072) {
        const int z = bx >> 10;
        const int ib = bx & 1023;
        const float* s = z == 0 ? Q : z == 1 ? K : V;
        unsigned short* d = z == 0 ? qc : z == 1 ? kc : vc;
        const int i0 = ib * 256 + tid;
        #pragma unroll
        for (int it = 0; it < 4; ++it) {
            const int i = i0 + it * 262144;
            const float4 v = reinterpret_cast<const float4*>(s)[i];
            uint2 pk;
            pk.x = cvt_pk_bf16(v.x, v.y);
            pk.y = cvt_pk_bf16(v.z, v.w);
            reinterpret_cast<uint2*>(d)[i] = pk;
        }
    } else {
        const int r4 = bx - 3072;
        const int z = r4 >> 8;
        const int tile = r4 & 255;
        const float* W = z == 0 ? w0 : z == 1 ? w1 : z == 2 ? w2 : w3;
        unsigned short* O = z == 0 ? o0 : z == 1 ? o1 : z == 2 ? o2 : o3;
        const int k0 = (tile >> 4) * 64, n0 = (tile & 15) * 64;

        const int r = tid >> 2, cbase = (tid & 3) * 16;
        #pragma unroll
        for (int i = 0; i < 4; ++i) {
            const int c = cbase + i * 4;
            const float4 v = *reinterpret_cast<const float4*>(&W[(size_t)(k0 + r) * N + n0 + c]);
            uint2 pk;
            pk.x = cvt_pk_bf16(v.x, v.y);
            pk.y = cvt_pk_bf16(v.z, v.w);
            const int byte = r * 128 + ((c * 2) ^ ((r & 7) << 4));
            *reinterpret_cast<uint2*>(reinterpret_cast<char*>(L) + byte) = pk;
        }
        __syncthreads();

        const int n = tid >> 2, kc2 = (tid & 3) * 16;
        ushortx8 v0, v1;
        #pragma unroll
        for (int j = 0; j < 8; ++j) {
            const int ka = kc2 + j, kb2 = kc2 + 8 + j;
            v0[j] = *reinterpret_cast<const unsigned short*>(
                reinterpret_cast<const char*>(L) + ka * 128 + ((n * 2) ^ ((ka & 7) << 4)));
            v1[j] = *reinterpret_cast<const unsigned short*>(
                reinterpret_cast<const char*>(L) + kb2 * 128 + ((n * 2) ^ ((kb2 & 7) << 4)));
        }
        unsigned short* op = &O[(size_t)(n0 + n) * N + k0 + kc2];
        *reinterpret_cast<ushortx8*>(op) = v0;
        *reinterpret_cast<ushortx8*>(op + 8) = v1;
    }
}

// ---------------------------------------------------------------------------
// bf16 GEMM, BK=64, both-sides swizzle (proven round-12; conflicts = 0).
// BN template: 128 (QKV) or 64 (out-proj: 512 blocks = 2/CU). 3D launch
// (the round-16 1D chunked swizzle regressed ~6 us -- reverted).
// ---------------------------------------------------------------------------
template <int MODE, int BN>
__global__ __launch_bounds__(256) void k_gemm_bf16(
    const unsigned short* __restrict__ A0, const unsigned short* __restrict__ A1,
    const unsigned short* __restrict__ A2,
    const unsigned short* __restrict__ B0, const unsigned short* __restrict__ B1,
    const unsigned short* __restrict__ B2,
    const float* __restrict__ bias0, const float* __restrict__ bias1,
    const float* __restrict__ bias2,
    void* C0, void* C1, void* C2)
{
    constexpr int K = 1024, N = 1024;
    constexpr int NJ = BN / 32;          // wave-col fragments
    const int z = MODE ? blockIdx.z : 0;
    const unsigned short* A  = z == 0 ? A0 : z == 1 ? A1 : A2;
    const unsigned short* Bt = z == 0 ? B0 : z == 1 ? B1 : B2;
    const float* bias        = z == 0 ? bias0 : z == 1 ? bias1 : bias2;
    void* C                  = z == 0 ? C0 : z == 1 ? C1 : C2;

    __shared__ unsigned short As[128 * 64];      // [row][k] 128-B rows
    __shared__ unsigned short Bs[BN * 64];

    const int tid  = threadIdx.x;
    const int lane = tid & 63;
    const int w    = tid >> 6;
    const int wr   = w >> 1, wc = w & 1;
    const int fr   = lane & 15, kg = lane >> 4;
    const int m0   = blockIdx.x * 128, n0 = blockIdx.y * BN;

    // staging: chunk = 8 rows (1 KB); lane covers row c*8+(l>>3), swizzled col
    const int srow8 = lane >> 3;                       // 0..7
    const int sswz  = ((lane & 7) ^ (lane >> 3)) * 8;  // pre-swizzled k-offset

    f32x4 acc[4][NJ] = {};

    for (int t = 0; t < K / 64; ++t) {
        const int k0 = t * 64;
        #pragma unroll
        for (int it = 0; it < 4; ++it) {
            const int c = w * 4 + it;
            gload16(&A[(size_t)(m0 + c * 8 + srow8) * K + k0 + sswz], &As[c * 512]);
            if (BN == 128)
                gload16(&Bt[(size_t)(n0 + c * 8 + srow8) * K + k0 + sswz], &Bs[c * 512]);
        }
        if (BN == 64) {
            #pragma unroll
            for (int it = 0; it < 2; ++it) {
                const int c = w * 2 + it;    // 8 chunks cover 64 rows
                gload16(&Bt[(size_t)(n0 + c * 8 + srow8) * K + k0 + sswz], &Bs[c * 512]);
            }
        }
        __syncthreads();

        const int rsw = (fr & 7) << 4;   // read-side XOR (byte)
        #pragma unroll
        for (int kh = 0; kh < 2; ++kh) {
            bf16x8 af[4], bfj[NJ];
            #pragma unroll
            for (int i = 0; i < 4; ++i)
                af[i] = *reinterpret_cast<const bf16x8*>(
                    reinterpret_cast<const char*>(As) +
                    (wr * 64 + i * 16 + fr) * 128 + ((kh * 64 + kg * 16) ^ rsw));
            #pragma unroll
            for (int j = 0; j < NJ; ++j)
                bfj[j] = *reinterpret_cast<const bf16x8*>(
                    reinterpret_cast<const char*>(Bs) +
                    (wc * (BN / 2) + j * 16 + fr) * 128 + ((kh * 64 + kg * 16) ^ rsw));
            #pragma unroll
            for (int i = 0; i < 4; ++i)
                #pragma unroll
                for (int j = 0; j < NJ; ++j)
                    acc[i][j] = mfma_16x16x32_bf16(af[i], bfj[j], acc[i][j]);
        }
        __syncthreads();
    }

    if (MODE == 1 && z == 2) {
        // V: store transposed per batch: vt[(bb*1024 + n)*2048 + s]
        unsigned short* vt = reinterpret_cast<unsigned short*>(C);
        #pragma unroll
        for (int i = 0; i < 4; ++i) {
            const int m = m0 + wr * 64 + i * 16 + kg * 4;
            const int bb = m >> 11, s = m & 2047;
            #pragma unroll
            for (int j = 0; j < NJ; ++j) {
                const int n = n0 + wc * (BN / 2) + j * 16 + fr;
                const float bv = bias[n];
                uint2 pk;
                pk.x = cvt_pk_bf16(acc[i][j][0] + bv, acc[i][j][1] + bv);
                pk.y = cvt_pk_bf16(acc[i][j][2] + bv, acc[i][j][3] + bv);
                *reinterpret_cast<uint2*>(&vt[((size_t)(bb * 1024 + n)) * 2048 + s]) = pk;
            }
        }
    } else if (MODE == 1) {
        // z==0 (Q): fold 1/sqrt(64) * log2(e) so attention uses native exp2.
        const float sc = (z == 0) ? 0.125f * 1.44269504088896340736f : 1.0f;
        unsigned short* Cb = reinterpret_cast<unsigned short*>(C);
        #pragma unroll
        for (int i = 0; i < 4; ++i) {
            const int m = m0 + wr * 64 + i * 16 + kg * 4;
            #pragma unroll
            for (int j = 0; j < NJ; ++j) {
                const int n = n0 + wc * (BN / 2) + j * 16 + fr;
                const float bv = bias[n];
                const unsigned int p0 = cvt_pk_bf16((acc[i][j][0] + bv) * sc, (acc[i][j][1] + bv) * sc);
                const unsigned int p1 = cvt_pk_bf16((acc[i][j][2] + bv) * sc, (acc[i][j][3] + bv) * sc);
                Cb[(size_t)(m + 0) * N + n] = (unsigned short)p0;
                Cb[(size_t)(m + 1) * N + n] = (unsigned short)(p0 >> 16);
                Cb[(size_t)(m + 2) * N + n] = (unsigned short)p1;
                Cb[(size_t)(m + 3) * N + n] = (unsigned short)(p1 >> 16);
            }
        }
    } else {
        float* Cf = reinterpret_cast<float*>(C);
        #pragma unroll
        for (int i = 0; i < 4; ++i) {
            const int m = m0 + wr * 64 + i * 16 + kg * 4;
            #pragma unroll
            for (int j = 0; j < NJ; ++j) {
                const int n = n0 + wc * (BN / 2) + j * 16 + fr;
                const float bv = bias[n];
                #pragma unroll
                for (int r = 0; r < 4; ++r)
                    Cf[(size_t)(m + r) * N + n] = acc[i][j][r] + bv;
            }
        }
    }
}

// ---------------------------------------------------------------------------
// V tail suffix sums (unchanged).
// ---------------------------------------------------------------------------
__global__ __launch_bounds__(256) void k_vtail(
    const unsigned short* __restrict__ vt, float* __restrict__ vtail)
{
    const int row = blockIdx.x * 4 + (threadIdx.x >> 6);
    const int l = threadIdx.x & 63;
    const unsigned short* p = &vt[(size_t)row * 2048 + l * 32];
    float s = 0.f;
    #pragma unroll
    for (int i = 0; i < 4; ++i) {
        ushortx8 v = *reinterpret_cast<const ushortx8*>(&p[i * 8]);
        #pragma unroll
        for (int e = 0; e < 8; ++e)
            s += __builtin_bit_cast(float, (unsigned int)v[e] << 16);
    }
    #pragma unroll
    for (int off = 1; off < 64; off <<= 1) {
        const float t = __shfl_down(s, off, 64);
        s += (l + off < 64) ? t : 0.f;
    }
    float tv = __shfl(s, (2 * l + 2) & 63, 64);
    if (l == 31) tv = 0.f;
    if (l < 32) vtail[(size_t)row * 32 + l] = tv;
}

// ---------------------------------------------------------------------------
// Attention (round-15 proven, best known: KVBLK=64, causal pair balancing,
// XCD chunked swizzle, dbuf swizzled LDS, 1-deep T14 prefetch, T5 setprio,
// exp2 path, reciprocal epilogue).
// ---------------------------------------------------------------------------
template <bool MASK>
DI void attn_tile(const unsigned char* KsB, const unsigned char* VtsB,
                  unsigned char* PB, bf16x8 qf0, bf16x8 qf1,
                  f32x4 (&o)[4], float& lsum, int w, int fr, int kg)
{
    const int sw = (fr & 7) << 4;
    #pragma unroll
    for (int j = 0; j < 4; ++j) {
        const int row = j * 16 + fr;
        const bf16x8 kf0 = *reinterpret_cast<const bf16x8*>(KsB + row * 128 + ((kg * 16) ^ sw));
        const bf16x8 kf1 = *reinterpret_cast<const bf16x8*>(KsB + row * 128 + ((64 + kg * 16) ^ sw));
        f32x4 s = {0.f, 0.f, 0.f, 0.f};
        __builtin_amdgcn_s_setprio(1);
        s = mfma_16x16x32_bf16(kf0, qf0, s);   // swapped: A=K rows (keys), B=Q
        s = mfma_16x16x32_bf16(kf1, qf1, s);
        __builtin_amdgcn_s_setprio(0);
        float p[4];
        #pragma unroll
        for (int r = 0; r < 4; ++r) {
            float e = exp2f(s[r]);             // q pre-scaled by log2e -> native 2^x
            if (MASK && (j * 16 + kg * 4 + r > w * 16 + fr)) e = 1.0f;  // exp(-1e-8)==1.0f
            p[r] = e;
            lsum += e;
        }
        uint2 pk;
        pk.x = cvt_pk_bf16(p[0], p[1]);
        pk.y = cvt_pk_bf16(p[2], p[3]);
        *reinterpret_cast<uint2*>(PB + fr * 128 + ((j * 32 + kg * 8) ^ sw)) = pk;
    }
    __builtin_amdgcn_s_setprio(1);
    #pragma unroll
    for (int kk = 0; kk < 2; ++kk) {
        const bf16x8 pf = *reinterpret_cast<const bf16x8*>(PB + fr * 128 + ((kk * 64 + kg * 16) ^ sw));
        #pragma unroll
        for (int n = 0; n < 4; ++n) {
            const int vrow = n * 16 + fr;
            const bf16x8 vf = *reinterpret_cast<const bf16x8*>(VtsB + vrow * 128 + ((kk * 64 + kg * 16) ^ sw));
            o[n] = mfma_16x16x32_bf16(pf, vf, o[n]);
        }
    }
    __builtin_amdgcn_s_setprio(0);
}

DI void attn_sweep(int qt,
                   const unsigned short* __restrict__ qp,
                   const unsigned short* __restrict__ kp,
                   const unsigned short* __restrict__ vt,
                   const float* __restrict__ vtail,
                   unsigned short* __restrict__ ctx,
                   unsigned char (*KsB)[64 * 128], unsigned char (*VtsB)[64 * 128],
                   unsigned char* PB, size_t baseQ, size_t baseV, int b, int h,
                   int w, int fr, int kg, int sr, int sc8, int wb0, int wb1)
{
    constexpr int S = 2048, D = 1024;
    const int q0 = qt * 64 + w * 16;

    bf16x8 qf0, qf1;
    {
        const size_t roff = baseQ + (size_t)(q0 + fr) * D;
        qf0 = *reinterpret_cast<const bf16x8*>(&qp[roff + kg * 8]);
        qf1 = *reinterpret_cast<const bf16x8*>(&qp[roff + 32 + kg * 8]);
    }

    f32x4 o[4] = {};
    float lsum = 0.f;
    const int NT = qt + 1;

    // prologue: stage tile 0 into buffer 0
    {
        const ushortx8 kr0 = *reinterpret_cast<const ushortx8*>(&kp[baseQ + (size_t)sr * D + sc8]);
        const ushortx8 kr1 = *reinterpret_cast<const ushortx8*>(&kp[baseQ + (size_t)(sr + 32) * D + sc8]);
        const ushortx8 vr0 = *reinterpret_cast<const ushortx8*>(&vt[baseV + (size_t)sr * S + sc8]);
        const ushortx8 vr1 = *reinterpret_cast<const ushortx8*>(&vt[baseV + (size_t)(sr + 32) * S + sc8]);
        *reinterpret_cast<ushortx8*>(KsB[0] + wb0)  = kr0;
        *reinterpret_cast<ushortx8*>(KsB[0] + wb1)  = kr1;
        *reinterpret_cast<ushortx8*>(VtsB[0] + wb0) = vr0;
        *reinterpret_cast<ushortx8*>(VtsB[0] + wb1) = vr1;
    }
    __syncthreads();

    for (int t = 0; t < NT; ++t) {
        const int cur = t & 1;
        const bool more = (t + 1 < NT);
        ushortx8 nk0, nk1, nv0, nv1;
        if (more) {   // T14: issue next-tile loads before compute
            const int kt1 = (t + 1) * 64;
            nk0 = *reinterpret_cast<const ushortx8*>(&kp[baseQ + (size_t)(kt1 + sr) * D + sc8]);
            nk1 = *reinterpret_cast<const ushortx8*>(&kp[baseQ + (size_t)(kt1 + sr + 32) * D + sc8]);
            nv0 = *reinterpret_cast<const ushortx8*>(&vt[baseV + (size_t)sr * S + kt1 + sc8]);
            nv1 = *reinterpret_cast<const ushortx8*>(&vt[baseV + (size_t)(sr + 32) * S + kt1 + sc8]);
        }
        if (more)
            attn_tile<false>(KsB[cur], VtsB[cur], PB, qf0, qf1, o, lsum, w, fr, kg);
        else
            attn_tile<true>(KsB[cur], VtsB[cur], PB, qf0, qf1, o, lsum, w, fr, kg);
        if (more) {   // write next tile into the other buffer (no extra barrier)
            const int nxt = cur ^ 1;
            *reinterpret_cast<ushortx8*>(KsB[nxt] + wb0)  = nk0;
            *reinterpret_cast<ushortx8*>(KsB[nxt] + wb1)  = nk1;
            *reinterpret_cast<ushortx8*>(VtsB[nxt] + wb0) = nv0;
            *reinterpret_cast<ushortx8*>(VtsB[nxt] + wb1) = nv1;
        }
        __syncthreads();
    }

    // full row sums: combine the 4 key-groups, add analytic tail count
    lsum += __shfl_xor(lsum, 16, 64);
    lsum += __shfl_xor(lsum, 32, 64);
    lsum += (float)(S - (qt + 1) * 64);

    float rlq[4];
    #pragma unroll
    for (int r = 0; r < 4; ++r) rlq[r] = 1.0f / __shfl(lsum, kg * 4 + r, 64);

    float tl[4];
    #pragma unroll
    for (int n = 0; n < 4; ++n)
        tl[n] = vtail[((size_t)(b * 1024) + h * 64 + n * 16 + fr) * 32 + qt];

    #pragma unroll
    for (int n = 0; n < 4; ++n)
        #pragma unroll
        for (int r = 0; r < 4; ++r) {
            const int qrow = q0 + kg * 4 + r;
            ctx[baseQ + (size_t)qrow * D + n * 16 + fr] = f2bf((o[n][r] + tl[n]) * rlq[r]);
        }
}

__global__ __launch_bounds__(256, 2) void k_attn(
    const unsigned short* __restrict__ qp,
    const unsigned short* __restrict__ kp,
    const unsigned short* __restrict__ vt,
    const float* __restrict__ vtail,
    unsigned short* __restrict__ ctx)
{
    constexpr int S = 2048, D = 1024;
    // T1 chunked XCD swizzle: G = (L%8)*64 + L/8 (bijective, 512 = 8*64):
    // each XCD's 64 resident blocks = 4 complete (h,b) panel groups (2 MB).
    const int L = blockIdx.x;
    const int G = (L & 7) * 64 + (L >> 3);
    const int p = G & 15;            // pair index 0..15
    const int h = (G >> 4) & 15;     // head
    const int b = G >> 8;            // batch

    __shared__ alignas(16) unsigned char KsB[2][64 * 128];     // dbuf K, swizzled
    __shared__ alignas(16) unsigned char VtsB[2][64 * 128];    // dbuf V, swizzled
    __shared__ alignas(16) unsigned char PlsB[4 * 16 * 128];   // per-wave P

    const int tid  = threadIdx.x;
    const int lane = tid & 63, w = tid >> 6;
    const int fr   = lane & 15, kg = lane >> 4;
    unsigned char* PB = PlsB + w * 2048;

    const size_t baseQ = ((size_t)b * S) * D + (size_t)h * 64;
    const size_t baseV = ((size_t)b * D + (size_t)h * 64) * S;

    const int sr  = tid >> 3;          // staging row 0..31
    const int sc8 = (tid & 7) * 8;     // element offset (8 bf16)
    const int wb0 = sr * 128 + (((tid & 7) * 16) ^ ((sr & 7) << 4));
    const int wb1 = (sr + 32) * 128 + (((tid & 7) * 16) ^ (((sr + 32) & 7) << 4));

    // pair (31-p, p): total key-tiles = (32-p) + (p+1) = 33, uniform
    attn_sweep(31 - p, qp, kp, vt, vtail, ctx, KsB, VtsB, PB,
               baseQ, baseV, b, h, w, fr, kg, sr, sc8, wb0, wb1);
    attn_sweep(p, qp, kp, vt, vtail, ctx, KsB, VtsB, PB,
               baseQ, baseV, b, h, w, fr, kg, sr, sc8, wb0, wb1);
}

// ---------------------------------------------------------------------------
extern "C" void kernel_launch(void* const* d_in, const int* in_sizes, int n_in,
                              void* d_out, int out_size, void* d_ws, size_t ws_size,
                              hipStream_t stream) {
    constexpr int B = 2, S = 2048, D = 1024;
    constexpr int M = B * S;                 // 4096
    constexpr size_t MD = (size_t)M * D;     // 4M elements

    const float* Q  = (const float*)d_in[0];
    const float* K  = (const float*)d_in[1];
    const float* V  = (const float*)d_in[2];
    const float* Wq = (const float*)d_in[4];
    const float* bq = (const float*)d_in[5];
    const float* Wk = (const float*)d_in[6];
    const float* bk = (const float*)d_in[7];
    const float* Wv = (const float*)d_in[8];
    const float* bv = (const float*)d_in[9];
    const float* Wo = (const float*)d_in[10];
    const float* bo = (const float*)d_in[11];

    // d_out (16 MiB, dead until final GEMM): qc (8 MiB) + kc (8 MiB)
    unsigned short* qc = (unsigned short*)d_out;
    unsigned short* kc = qc + MD;
    // d_ws (40 MiB): qb, kb, vtg, vc/ctx (8 MiB each) + Wto/Wtq/Wtk/Wtv (2 MiB each)
    char* ws = (char*)d_ws;
    unsigned short* qb  = (unsigned short*)(ws);
    unsigned short* kb  = (unsigned short*)(ws + (8u << 20));
    unsigned short* vtg = (unsigned short*)(ws + (16u << 20));
    unsigned short* vc  = (unsigned short*)(ws + (24u << 20));
    unsigned short* Wto = (unsigned short*)(ws + (32u << 20));
    unsigned short* Wtq = (unsigned short*)(ws + (34u << 20));
    unsigned short* Wtk = (unsigned short*)(ws + (36u << 20));
    unsigned short* Wtv = (unsigned short*)(ws + (38u << 20));
    unsigned short* ctx = vc;                       // aliases vc (dead by then)
    float* vtail        = (float*)Wtq;              // aliases Wtq (dead by then)

    dim3 blk(256);
    k_prep<<<dim3(4096), blk, 0, stream>>>(
        Q, K, V, qc, kc, vc, Wq, Wk, Wv, Wo, Wtq, Wtk, Wtv, Wto);
    k_gemm_bf16<1, 128><<<dim3(M / 128, D / 128, 3), blk, 0, stream>>>(
        qc, kc, vc, Wtq, Wtk, Wtv, bq, bk, bv, qb, kb, vtg);
    k_vtail<<<dim3((B * D) / 4), blk, 0, stream>>>(vtg, vtail);
    k_attn<<<dim3(512), blk, 0, stream>>>(qb, kb, vtg, vtail, ctx);
    k_gemm_bf16<0, 64><<<dim3(M / 128, D / 64, 1), blk, 0, stream>>>(
        ctx, ctx, ctx, Wto, Wto, Wto, bo, bo, bo, d_out, d_out, d_out);
}

// Round 18
// 122.684 us; speedup vs baseline: 1.1094x; 1.0072x over previous
//
#include <hip/hip_runtime.h>
#include <hip/hip_bf16.h>
#include <stdint.h>
#include <math.h>

#define DI __device__ __forceinline__

typedef __bf16 bf16x8 __attribute__((ext_vector_type(8)));
typedef float f32x4 __attribute__((ext_vector_type(4)));
typedef unsigned short ushortx8 __attribute__((ext_vector_type(8)));

// fp32 -> bf16 round-to-nearest-even (scalar path)
DI unsigned short f2bf(float f) {
    unsigned int u = __builtin_bit_cast(unsigned int, f);
    u += 0x7fffu + ((u >> 16) & 1u);
    return (unsigned short)(u >> 16);
}

// packed fp32x2 -> bf16x2 (1 VALU op). lo -> bits 0-15, hi -> bits 16-31.
DI unsigned int cvt_pk_bf16(float lo, float hi) {
    unsigned int r;
    asm("v_cvt_pk_bf16_f32 %0, %1, %2" : "=v"(r) : "v"(lo), "v"(hi));
    return r;
}

DI f32x4 mfma_16x16x32_bf16(bf16x8 a, bf16x8 b, f32x4 c) {
    return __builtin_amdgcn_mfma_f32_16x16x32_bf16(a, b, c, 0, 0, 0);
}

// async global->LDS, 16B per lane. LDS dest: wave-uniform base + lane*16.
DI void gload16(const unsigned short* g, unsigned short* l) {
    __builtin_amdgcn_global_load_lds(
        (const __attribute__((address_space(1))) void*)g,
        (__attribute__((address_space(3))) void*)l, 16, 0, 0);
}

// ---------------------------------------------------------------------------
// k_prep: fused prep (proven). Blocks 0..3071: fp32->bf16 cvt of Q/K/V.
// Blocks 3072..4095: W -> Wt bf16 transpose (4 matrices, 64x64 tiles).
// ---------------------------------------------------------------------------
__global__ __launch_bounds__(256) void k_prep(
    const float* __restrict__ Q, const float* __restrict__ K, const float* __restrict__ V,
    unsigned short* __restrict__ qc, unsigned short* __restrict__ kc, unsigned short* __restrict__ vc,
    const float* __restrict__ w0, const float* __restrict__ w1,
    const float* __restrict__ w2, const float* __restrict__ w3,
    unsigned short* __restrict__ o0, unsigned short* __restrict__ o1,
    unsigned short* __restrict__ o2, unsigned short* __restrict__ o3)
{
    constexpr int N = 1024;
    __shared__ unsigned short L[64 * 64];
    const int bx = blockIdx.x;
    const int tid = threadIdx.x;

    if (bx < 3072) {
        const int z = bx >> 10;
        const int ib = bx & 1023;
        const float* s = z == 0 ? Q : z == 1 ? K : V;
        unsigned short* d = z == 0 ? qc : z == 1 ? kc : vc;
        const int i0 = ib * 256 + tid;
        #pragma unroll
        for (int it = 0; it < 4; ++it) {
            const int i = i0 + it * 262144;
            const float4 v = reinterpret_cast<const float4*>(s)[i];
            uint2 pk;
            pk.x = cvt_pk_bf16(v.x, v.y);
            pk.y = cvt_pk_bf16(v.z, v.w);
            reinterpret_cast<uint2*>(d)[i] = pk;
        }
    } else {
        const int r4 = bx - 3072;
        const int z = r4 >> 8;
        const int tile = r4 & 255;
        const float* W = z == 0 ? w0 : z == 1 ? w1 : z == 2 ? w2 : w3;
        unsigned short* O = z == 0 ? o0 : z == 1 ? o1 : z == 2 ? o2 : o3;
        const int k0 = (tile >> 4) * 64, n0 = (tile & 15) * 64;

        const int r = tid >> 2, cbase = (tid & 3) * 16;
        #pragma unroll
        for (int i = 0; i < 4; ++i) {
            const int c = cbase + i * 4;
            const float4 v = *reinterpret_cast<const float4*>(&W[(size_t)(k0 + r) * N + n0 + c]);
            uint2 pk;
            pk.x = cvt_pk_bf16(v.x, v.y);
            pk.y = cvt_pk_bf16(v.z, v.w);
            const int byte = r * 128 + ((c * 2) ^ ((r & 7) << 4));
            *reinterpret_cast<uint2*>(reinterpret_cast<char*>(L) + byte) = pk;
        }
        __syncthreads();

        const int n = tid >> 2, kc2 = (tid & 3) * 16;
        ushortx8 v0, v1;
        #pragma unroll
        for (int j = 0; j < 8; ++j) {
            const int ka = kc2 + j, kb2 = kc2 + 8 + j;
            v0[j] = *reinterpret_cast<const unsigned short*>(
                reinterpret_cast<const char*>(L) + ka * 128 + ((n * 2) ^ ((ka & 7) << 4)));
            v1[j] = *reinterpret_cast<const unsigned short*>(
                reinterpret_cast<const char*>(L) + kb2 * 128 + ((n * 2) ^ ((kb2 & 7) << 4)));
        }
        unsigned short* op = &O[(size_t)(n0 + n) * N + k0 + kc2];
        *reinterpret_cast<ushortx8*>(op) = v0;
        *reinterpret_cast<ushortx8*>(op + 8) = v1;
    }
}

// ---------------------------------------------------------------------------
// bf16 GEMM, BK=64, both-sides swizzle (proven; conflicts = 0). BN=128 (QKV)
// or 64 (out-proj, 512 blocks = 2/CU). 3D launch.
// ---------------------------------------------------------------------------
template <int MODE, int BN>
__global__ __launch_bounds__(256) void k_gemm_bf16(
    const unsigned short* __restrict__ A0, const unsigned short* __restrict__ A1,
    const unsigned short* __restrict__ A2,
    const unsigned short* __restrict__ B0, const unsigned short* __restrict__ B1,
    const unsigned short* __restrict__ B2,
    const float* __restrict__ bias0, const float* __restrict__ bias1,
    const float* __restrict__ bias2,
    void* C0, void* C1, void* C2)
{
    constexpr int K = 1024, N = 1024;
    constexpr int NJ = BN / 32;          // wave-col fragments
    const int z = MODE ? blockIdx.z : 0;
    const unsigned short* A  = z == 0 ? A0 : z == 1 ? A1 : A2;
    const unsigned short* Bt = z == 0 ? B0 : z == 1 ? B1 : B2;
    const float* bias        = z == 0 ? bias0 : z == 1 ? bias1 : bias2;
    void* C                  = z == 0 ? C0 : z == 1 ? C1 : C2;

    __shared__ unsigned short As[128 * 64];      // [row][k] 128-B rows
    __shared__ unsigned short Bs[BN * 64];

    const int tid  = threadIdx.x;
    const int lane = tid & 63;
    const int w    = tid >> 6;
    const int wr   = w >> 1, wc = w & 1;
    const int fr   = lane & 15, kg = lane >> 4;
    const int m0   = blockIdx.x * 128, n0 = blockIdx.y * BN;

    const int srow8 = lane >> 3;                       // 0..7
    const int sswz  = ((lane & 7) ^ (lane >> 3)) * 8;  // pre-swizzled k-offset

    f32x4 acc[4][NJ] = {};

    for (int t = 0; t < K / 64; ++t) {
        const int k0 = t * 64;
        #pragma unroll
        for (int it = 0; it < 4; ++it) {
            const int c = w * 4 + it;
            gload16(&A[(size_t)(m0 + c * 8 + srow8) * K + k0 + sswz], &As[c * 512]);
            if (BN == 128)
                gload16(&Bt[(size_t)(n0 + c * 8 + srow8) * K + k0 + sswz], &Bs[c * 512]);
        }
        if (BN == 64) {
            #pragma unroll
            for (int it = 0; it < 2; ++it) {
                const int c = w * 2 + it;    // 8 chunks cover 64 rows
                gload16(&Bt[(size_t)(n0 + c * 8 + srow8) * K + k0 + sswz], &Bs[c * 512]);
            }
        }
        __syncthreads();

        const int rsw = (fr & 7) << 4;   // read-side XOR (byte)
        #pragma unroll
        for (int kh = 0; kh < 2; ++kh) {
            bf16x8 af[4], bfj[NJ];
            #pragma unroll
            for (int i = 0; i < 4; ++i)
                af[i] = *reinterpret_cast<const bf16x8*>(
                    reinterpret_cast<const char*>(As) +
                    (wr * 64 + i * 16 + fr) * 128 + ((kh * 64 + kg * 16) ^ rsw));
            #pragma unroll
            for (int j = 0; j < NJ; ++j)
                bfj[j] = *reinterpret_cast<const bf16x8*>(
                    reinterpret_cast<const char*>(Bs) +
                    (wc * (BN / 2) + j * 16 + fr) * 128 + ((kh * 64 + kg * 16) ^ rsw));
            #pragma unroll
            for (int i = 0; i < 4; ++i)
                #pragma unroll
                for (int j = 0; j < NJ; ++j)
                    acc[i][j] = mfma_16x16x32_bf16(af[i], bfj[j], acc[i][j]);
        }
        __syncthreads();
    }

    if (MODE == 1 && z == 2) {
        // V: store transposed per batch: vt[(bb*1024 + n)*2048 + s]
        unsigned short* vt = reinterpret_cast<unsigned short*>(C);
        #pragma unroll
        for (int i = 0; i < 4; ++i) {
            const int m = m0 + wr * 64 + i * 16 + kg * 4;
            const int bb = m >> 11, s = m & 2047;
            #pragma unroll
            for (int j = 0; j < NJ; ++j) {
                const int n = n0 + wc * (BN / 2) + j * 16 + fr;
                const float bv = bias[n];
                uint2 pk;
                pk.x = cvt_pk_bf16(acc[i][j][0] + bv, acc[i][j][1] + bv);
                pk.y = cvt_pk_bf16(acc[i][j][2] + bv, acc[i][j][3] + bv);
                *reinterpret_cast<uint2*>(&vt[((size_t)(bb * 1024 + n)) * 2048 + s]) = pk;
            }
        }
    } else if (MODE == 1) {
        // z==0 (Q): fold 1/sqrt(64) * log2(e) so attention uses native exp2.
        const float sc = (z == 0) ? 0.125f * 1.44269504088896340736f : 1.0f;
        unsigned short* Cb = reinterpret_cast<unsigned short*>(C);
        #pragma unroll
        for (int i = 0; i < 4; ++i) {
            const int m = m0 + wr * 64 + i * 16 + kg * 4;
            #pragma unroll
            for (int j = 0; j < NJ; ++j) {
                const int n = n0 + wc * (BN / 2) + j * 16 + fr;
                const float bv = bias[n];
                const unsigned int p0 = cvt_pk_bf16((acc[i][j][0] + bv) * sc, (acc[i][j][1] + bv) * sc);
                const unsigned int p1 = cvt_pk_bf16((acc[i][j][2] + bv) * sc, (acc[i][j][3] + bv) * sc);
                Cb[(size_t)(m + 0) * N + n] = (unsigned short)p0;
                Cb[(size_t)(m + 1) * N + n] = (unsigned short)(p0 >> 16);
                Cb[(size_t)(m + 2) * N + n] = (unsigned short)p1;
                Cb[(size_t)(m + 3) * N + n] = (unsigned short)(p1 >> 16);
            }
        }
    } else {
        float* Cf = reinterpret_cast<float*>(C);
        #pragma unroll
        for (int i = 0; i < 4; ++i) {
            const int m = m0 + wr * 64 + i * 16 + kg * 4;
            #pragma unroll
            for (int j = 0; j < NJ; ++j) {
                const int n = n0 + wc * (BN / 2) + j * 16 + fr;
                const float bv = bias[n];
                #pragma unroll
                for (int r = 0; r < 4; ++r)
                    Cf[(size_t)(m + r) * N + n] = acc[i][j][r] + bv;
            }
        }
    }
}

// ---------------------------------------------------------------------------
// V tail suffix sums (unchanged).
// ---------------------------------------------------------------------------
__global__ __launch_bounds__(256) void k_vtail(
    const unsigned short* __restrict__ vt, float* __restrict__ vtail)
{
    const int row = blockIdx.x * 4 + (threadIdx.x >> 6);
    const int l = threadIdx.x & 63;
    const unsigned short* p = &vt[(size_t)row * 2048 + l * 32];
    float s = 0.f;
    #pragma unroll
    for (int i = 0; i < 4; ++i) {
        ushortx8 v = *reinterpret_cast<const ushortx8*>(&p[i * 8]);
        #pragma unroll
        for (int e = 0; e < 8; ++e)
            s += __builtin_bit_cast(float, (unsigned int)v[e] << 16);
    }
    #pragma unroll
    for (int off = 1; off < 64; off <<= 1) {
        const float t = __shfl_down(s, off, 64);
        s += (l + off < 64) ? t : 0.f;
    }
    float tv = __shfl(s, (2 * l + 2) & 63, 64);
    if (l == 31) tv = 0.f;
    if (l < 32) vtail[(size_t)row * 32 + l] = tv;
}

// ---------------------------------------------------------------------------
// Attention (round-15 structure) + ones-column row-sum: the softmax
// denominator comes out of the PV MFMA pipe (oS = mfma(P, ones)) instead of
// a 16-deep serial VALU add chain per tile, and lands in exactly the lane
// that needs it (row=kg*4+r = q-row) -> final shuffles deleted too.
// ---------------------------------------------------------------------------
template <bool MASK>
DI void attn_tile(const unsigned char* KsB, const unsigned char* VtsB,
                  unsigned char* PB, bf16x8 qf0, bf16x8 qf1,
                  f32x4 (&o)[4], f32x4& oS, int w, int fr, int kg)
{
    const int sw = (fr & 7) << 4;
    #pragma unroll
    for (int j = 0; j < 4; ++j) {
        const int row = j * 16 + fr;
        const bf16x8 kf0 = *reinterpret_cast<const bf16x8*>(KsB + row * 128 + ((kg * 16) ^ sw));
        const bf16x8 kf1 = *reinterpret_cast<const bf16x8*>(KsB + row * 128 + ((64 + kg * 16) ^ sw));
        f32x4 s = {0.f, 0.f, 0.f, 0.f};
        __builtin_amdgcn_s_setprio(1);
        s = mfma_16x16x32_bf16(kf0, qf0, s);   // swapped: A=K rows (keys), B=Q
        s = mfma_16x16x32_bf16(kf1, qf1, s);
        __builtin_amdgcn_s_setprio(0);
        float p[4];
        #pragma unroll
        for (int r = 0; r < 4; ++r) {
            float e = exp2f(s[r]);             // q pre-scaled by log2e -> native 2^x
            if (MASK && (j * 16 + kg * 4 + r > w * 16 + fr)) e = 1.0f;  // exp(-1e-8)==1.0f
            p[r] = e;
        }
        uint2 pk;
        pk.x = cvt_pk_bf16(p[0], p[1]);
        pk.y = cvt_pk_bf16(p[2], p[3]);
        *reinterpret_cast<uint2*>(PB + fr * 128 + ((j * 32 + kg * 8) ^ sw)) = pk;
    }
    // all-ones B fragment (bf16 1.0 broadcast) for the P row-sum MFMA
    bf16x8 ones;
    #pragma unroll
    for (int b = 0; b < 8; ++b) ones[b] = (__bf16)1.0f;
    __builtin_amdgcn_s_setprio(1);
    #pragma unroll
    for (int kk = 0; kk < 2; ++kk) {
        const bf16x8 pf = *reinterpret_cast<const bf16x8*>(PB + fr * 128 + ((kk * 64 + kg * 16) ^ sw));
        #pragma unroll
        for (int n = 0; n < 4; ++n) {
            const int vrow = n * 16 + fr;
            const bf16x8 vf = *reinterpret_cast<const bf16x8*>(VtsB + vrow * 128 + ((kk * 64 + kg * 16) ^ sw));
            o[n] = mfma_16x16x32_bf16(pf, vf, o[n]);
        }
        oS = mfma_16x16x32_bf16(pf, ones, oS);   // denominator via matrix pipe
    }
    __builtin_amdgcn_s_setprio(0);
}

DI void attn_sweep(int qt,
                   const unsigned short* __restrict__ qp,
                   const unsigned short* __restrict__ kp,
                   const unsigned short* __restrict__ vt,
                   const float* __restrict__ vtail,
                   unsigned short* __restrict__ ctx,
                   unsigned char (*KsB)[64 * 128], unsigned char (*VtsB)[64 * 128],
                   unsigned char* PB, size_t baseQ, size_t baseV, int b, int h,
                   int w, int fr, int kg, int sr, int sc8, int wb0, int wb1)
{
    constexpr int S = 2048, D = 1024;
    const int q0 = qt * 64 + w * 16;

    bf16x8 qf0, qf1;
    {
        const size_t roff = baseQ + (size_t)(q0 + fr) * D;
        qf0 = *reinterpret_cast<const bf16x8*>(&qp[roff + kg * 8]);
        qf1 = *reinterpret_cast<const bf16x8*>(&qp[roff + 32 + kg * 8]);
    }

    f32x4 o[4] = {};
    f32x4 oS = {};
    const int NT = qt + 1;

    // prologue: stage tile 0 into buffer 0
    {
        const ushortx8 kr0 = *reinterpret_cast<const ushortx8*>(&kp[baseQ + (size_t)sr * D + sc8]);
        const ushortx8 kr1 = *reinterpret_cast<const ushortx8*>(&kp[baseQ + (size_t)(sr + 32) * D + sc8]);
        const ushortx8 vr0 = *reinterpret_cast<const ushortx8*>(&vt[baseV + (size_t)sr * S + sc8]);
        const ushortx8 vr1 = *reinterpret_cast<const ushortx8*>(&vt[baseV + (size_t)(sr + 32) * S + sc8]);
        *reinterpret_cast<ushortx8*>(KsB[0] + wb0)  = kr0;
        *reinterpret_cast<ushortx8*>(KsB[0] + wb1)  = kr1;
        *reinterpret_cast<ushortx8*>(VtsB[0] + wb0) = vr0;
        *reinterpret_cast<ushortx8*>(VtsB[0] + wb1) = vr1;
    }
    __syncthreads();

    for (int t = 0; t < NT; ++t) {
        const int cur = t & 1;
        const bool more = (t + 1 < NT);
        ushortx8 nk0, nk1, nv0, nv1;
        if (more) {   // T14: issue next-tile loads before compute
            const int kt1 = (t + 1) * 64;
            nk0 = *reinterpret_cast<const ushortx8*>(&kp[baseQ + (size_t)(kt1 + sr) * D + sc8]);
            nk1 = *reinterpret_cast<const ushortx8*>(&kp[baseQ + (size_t)(kt1 + sr + 32) * D + sc8]);
            nv0 = *reinterpret_cast<const ushortx8*>(&vt[baseV + (size_t)sr * S + kt1 + sc8]);
            nv1 = *reinterpret_cast<const ushortx8*>(&vt[baseV + (size_t)(sr + 32) * S + kt1 + sc8]);
        }
        if (more)
            attn_tile<false>(KsB[cur], VtsB[cur], PB, qf0, qf1, o, oS, w, fr, kg);
        else
            attn_tile<true>(KsB[cur], VtsB[cur], PB, qf0, qf1, o, oS, w, fr, kg);
        if (more) {   // write next tile into the other buffer (no extra barrier)
            const int nxt = cur ^ 1;
            *reinterpret_cast<ushortx8*>(KsB[nxt] + wb0)  = nk0;
            *reinterpret_cast<ushortx8*>(KsB[nxt] + wb1)  = nk1;
            *reinterpret_cast<ushortx8*>(VtsB[nxt] + wb0) = nv0;
            *reinterpret_cast<ushortx8*>(VtsB[nxt] + wb1) = nv1;
        }
        __syncthreads();
    }

    // denominator: oS[r] already holds q-row (q0 + kg*4 + r)'s P-sum (same
    // across fr lanes); add analytic tail count, reciprocal once.
    const float tailc = (float)(S - (qt + 1) * 64);
    float rlq[4];
    #pragma unroll
    for (int r = 0; r < 4; ++r) rlq[r] = 1.0f / (oS[r] + tailc);

    float tl[4];
    #pragma unroll
    for (int n = 0; n < 4; ++n)
        tl[n] = vtail[((size_t)(b * 1024) + h * 64 + n * 16 + fr) * 32 + qt];

    #pragma unroll
    for (int n = 0; n < 4; ++n)
        #pragma unroll
        for (int r = 0; r < 4; ++r) {
            const int qrow = q0 + kg * 4 + r;
            ctx[baseQ + (size_t)qrow * D + n * 16 + fr] = f2bf((o[n][r] + tl[n]) * rlq[r]);
        }
}

__global__ __launch_bounds__(256, 2) void k_attn(
    const unsigned short* __restrict__ qp,
    const unsigned short* __restrict__ kp,
    const unsigned short* __restrict__ vt,
    const float* __restrict__ vtail,
    unsigned short* __restrict__ ctx)
{
    constexpr int S = 2048, D = 1024;
    // T1 chunked XCD swizzle: G = (L%8)*64 + L/8 (bijective, 512 = 8*64):
    // each XCD's 64 resident blocks = 4 complete (h,b) panel groups (2 MB).
    const int L = blockIdx.x;
    const int G = (L & 7) * 64 + (L >> 3);
    const int p = G & 15;            // pair index 0..15
    const int h = (G >> 4) & 15;     // head
    const int b = G >> 8;            // batch

    __shared__ alignas(16) unsigned char KsB[2][64 * 128];     // dbuf K, swizzled
    __shared__ alignas(16) unsigned char VtsB[2][64 * 128];    // dbuf V, swizzled
    __shared__ alignas(16) unsigned char PlsB[4 * 16 * 128];   // per-wave P

    const int tid  = threadIdx.x;
    const int lane = tid & 63, w = tid >> 6;
    const int fr   = lane & 15, kg = lane >> 4;
    unsigned char* PB = PlsB + w * 2048;

    const size_t baseQ = ((size_t)b * S) * D + (size_t)h * 64;
    const size_t baseV = ((size_t)b * D + (size_t)h * 64) * S;

    const int sr  = tid >> 3;          // staging row 0..31
    const int sc8 = (tid & 7) * 8;     // element offset (8 bf16)
    const int wb0 = sr * 128 + (((tid & 7) * 16) ^ ((sr & 7) << 4));
    const int wb1 = (sr + 32) * 128 + (((tid & 7) * 16) ^ (((sr + 32) & 7) << 4));

    // pair (31-p, p): total key-tiles = (32-p) + (p+1) = 33, uniform
    attn_sweep(31 - p, qp, kp, vt, vtail, ctx, KsB, VtsB, PB,
               baseQ, baseV, b, h, w, fr, kg, sr, sc8, wb0, wb1);
    attn_sweep(p, qp, kp, vt, vtail, ctx, KsB, VtsB, PB,
               baseQ, baseV, b, h, w, fr, kg, sr, sc8, wb0, wb1);
}

// ---------------------------------------------------------------------------
extern "C" void kernel_launch(void* const* d_in, const int* in_sizes, int n_in,
                              void* d_out, int out_size, void* d_ws, size_t ws_size,
                              hipStream_t stream) {
    constexpr int B = 2, S = 2048, D = 1024;
    constexpr int M = B * S;                 // 4096
    constexpr size_t MD = (size_t)M * D;     // 4M elements

    const float* Q  = (const float*)d_in[0];
    const float* K  = (const float*)d_in[1];
    const float* V  = (const float*)d_in[2];
    const float* Wq = (const float*)d_in[4];
    const float* bq = (const float*)d_in[5];
    const float* Wk = (const float*)d_in[6];
    const float* bk = (const float*)d_in[7];
    const float* Wv = (const float*)d_in[8];
    const float* bv = (const float*)d_in[9];
    const float* Wo = (const float*)d_in[10];
    const float* bo = (const float*)d_in[11];

    // d_out (16 MiB, dead until final GEMM): qc (8 MiB) + kc (8 MiB)
    unsigned short* qc = (unsigned short*)d_out;
    unsigned short* kc = qc + MD;
    // d_ws (40 MiB): qb, kb, vtg, vc/ctx (8 MiB each) + Wto/Wtq/Wtk/Wtv (2 MiB each)
    char* ws = (char*)d_ws;
    unsigned short* qb  = (unsigned short*)(ws);
    unsigned short* kb  = (unsigned short*)(ws + (8u << 20));
    unsigned short* vtg = (unsigned short*)(ws + (16u << 20));
    unsigned short* vc  = (unsigned short*)(ws + (24u << 20));
    unsigned short* Wto = (unsigned short*)(ws + (32u << 20));
    unsigned short* Wtq = (unsigned short*)(ws + (34u << 20));
    unsigned short* Wtk = (unsigned short*)(ws + (36u << 20));
    unsigned short* Wtv = (unsigned short*)(ws + (38u << 20));
    unsigned short* ctx = vc;                       // aliases vc (dead by then)
    float* vtail        = (float*)Wtq;              // aliases Wtq (dead by then)

    dim3 blk(256);
    k_prep<<<dim3(4096), blk, 0, stream>>>(
        Q, K, V, qc, kc, vc, Wq, Wk, Wv, Wo, Wtq, Wtk, Wtv, Wto);
    k_gemm_bf16<1, 128><<<dim3(M / 128, D / 128, 3), blk, 0, stream>>>(
        qc, kc, vc, Wtq, Wtk, Wtv, bq, bk, bv, qb, kb, vtg);
    k_vtail<<<dim3((B * D) / 4), blk, 0, stream>>>(vtg, vtail);
    k_attn<<<dim3(512), blk, 0, stream>>>(qb, kb, vtg, vtail, ctx);
    k_gemm_bf16<0, 64><<<dim3(M / 128, D / 64, 1), blk, 0, stream>>>(
        ctx, ctx, ctx, Wto, Wto, Wto, bo, bo, bo, d_out, d_out, d_out);
}

// Round 19
// 121.750 us; speedup vs baseline: 1.1179x; 1.0077x over previous
//
#include <hip/hip_runtime.h>
#include <hip/hip_bf16.h>
#include <stdint.h>
#include <math.h>

#define DI __device__ __forceinline__

typedef __bf16 bf16x8 __attribute__((ext_vector_type(8)));
typedef float f32x4 __attribute__((ext_vector_type(4)));
typedef unsigned short ushortx8 __attribute__((ext_vector_type(8)));

// fp32 -> bf16 round-to-nearest-even (scalar path)
DI unsigned short f2bf(float f) {
    unsigned int u = __builtin_bit_cast(unsigned int, f);
    u += 0x7fffu + ((u >> 16) & 1u);
    return (unsigned short)(u >> 16);
}

// packed fp32x2 -> bf16x2 (1 VALU op). lo -> bits 0-15, hi -> bits 16-31.
DI unsigned int cvt_pk_bf16(float lo, float hi) {
    unsigned int r;
    asm("v_cvt_pk_bf16_f32 %0, %1, %2" : "=v"(r) : "v"(lo), "v"(hi));
    return r;
}

DI f32x4 mfma_16x16x32_bf16(bf16x8 a, bf16x8 b, f32x4 c) {
    return __builtin_amdgcn_mfma_f32_16x16x32_bf16(a, b, c, 0, 0, 0);
}

// async global->LDS, 16B per lane. LDS dest: wave-uniform base + lane*16.
DI void gload16(const unsigned short* g, unsigned short* l) {
    __builtin_amdgcn_global_load_lds(
        (const __attribute__((address_space(1))) void*)g,
        (__attribute__((address_space(3))) void*)l, 16, 0, 0);
}

// ---------------------------------------------------------------------------
// k_prep: fused prep (proven). Blocks 0..3071: fp32->bf16 cvt of Q/K/V.
// Blocks 3072..4095: W -> Wt bf16 transpose (4 matrices, 64x64 tiles).
// ---------------------------------------------------------------------------
__global__ __launch_bounds__(256) void k_prep(
    const float* __restrict__ Q, const float* __restrict__ K, const float* __restrict__ V,
    unsigned short* __restrict__ qc, unsigned short* __restrict__ kc, unsigned short* __restrict__ vc,
    const float* __restrict__ w0, const float* __restrict__ w1,
    const float* __restrict__ w2, const float* __restrict__ w3,
    unsigned short* __restrict__ o0, unsigned short* __restrict__ o1,
    unsigned short* __restrict__ o2, unsigned short* __restrict__ o3)
{
    constexpr int N = 1024;
    __shared__ unsigned short L[64 * 64];
    const int bx = blockIdx.x;
    const int tid = threadIdx.x;

    if (bx < 3072) {
        const int z = bx >> 10;
        const int ib = bx & 1023;
        const float* s = z == 0 ? Q : z == 1 ? K : V;
        unsigned short* d = z == 0 ? qc : z == 1 ? kc : vc;
        const int i0 = ib * 256 + tid;
        #pragma unroll
        for (int it = 0; it < 4; ++it) {
            const int i = i0 + it * 262144;
            const float4 v = reinterpret_cast<const float4*>(s)[i];
            uint2 pk;
            pk.x = cvt_pk_bf16(v.x, v.y);
            pk.y = cvt_pk_bf16(v.z, v.w);
            reinterpret_cast<uint2*>(d)[i] = pk;
        }
    } else {
        const int r4 = bx - 3072;
        const int z = r4 >> 8;
        const int tile = r4 & 255;
        const float* W = z == 0 ? w0 : z == 1 ? w1 : z == 2 ? w2 : w3;
        unsigned short* O = z == 0 ? o0 : z == 1 ? o1 : z == 2 ? o2 : o3;
        const int k0 = (tile >> 4) * 64, n0 = (tile & 15) * 64;

        const int r = tid >> 2, cbase = (tid & 3) * 16;
        #pragma unroll
        for (int i = 0; i < 4; ++i) {
            const int c = cbase + i * 4;
            const float4 v = *reinterpret_cast<const float4*>(&W[(size_t)(k0 + r) * N + n0 + c]);
            uint2 pk;
            pk.x = cvt_pk_bf16(v.x, v.y);
            pk.y = cvt_pk_bf16(v.z, v.w);
            const int byte = r * 128 + ((c * 2) ^ ((r & 7) << 4));
            *reinterpret_cast<uint2*>(reinterpret_cast<char*>(L) + byte) = pk;
        }
        __syncthreads();

        const int n = tid >> 2, kc2 = (tid & 3) * 16;
        ushortx8 v0, v1;
        #pragma unroll
        for (int j = 0; j < 8; ++j) {
            const int ka = kc2 + j, kb2 = kc2 + 8 + j;
            v0[j] = *reinterpret_cast<const unsigned short*>(
                reinterpret_cast<const char*>(L) + ka * 128 + ((n * 2) ^ ((ka & 7) << 4)));
            v1[j] = *reinterpret_cast<const unsigned short*>(
                reinterpret_cast<const char*>(L) + kb2 * 128 + ((n * 2) ^ ((kb2 & 7) << 4)));
        }
        unsigned short* op = &O[(size_t)(n0 + n) * N + k0 + kc2];
        *reinterpret_cast<ushortx8*>(op) = v0;
        *reinterpret_cast<ushortx8*>(op + 8) = v1;
    }
}

// ---------------------------------------------------------------------------
// bf16 GEMM, BK=64, both-sides swizzle (proven; conflicts = 0). BN=64 for
// BOTH QKV and out-proj now: the BN=64 instantiation measured ~25%/problem
// faster than BN=128 on the identical shape (out-proj, rounds 15-18) via
// doubled grid (6 blocks/CU for QKV) + halved acc-VGPR. 3D launch.
// ---------------------------------------------------------------------------
template <int MODE, int BN>
__global__ __launch_bounds__(256) void k_gemm_bf16(
    const unsigned short* __restrict__ A0, const unsigned short* __restrict__ A1,
    const unsigned short* __restrict__ A2,
    const unsigned short* __restrict__ B0, const unsigned short* __restrict__ B1,
    const unsigned short* __restrict__ B2,
    const float* __restrict__ bias0, const float* __restrict__ bias1,
    const float* __restrict__ bias2,
    void* C0, void* C1, void* C2)
{
    constexpr int K = 1024, N = 1024;
    constexpr int NJ = BN / 32;          // wave-col fragments
    const int z = MODE ? blockIdx.z : 0;
    const unsigned short* A  = z == 0 ? A0 : z == 1 ? A1 : A2;
    const unsigned short* Bt = z == 0 ? B0 : z == 1 ? B1 : B2;
    const float* bias        = z == 0 ? bias0 : z == 1 ? bias1 : bias2;
    void* C                  = z == 0 ? C0 : z == 1 ? C1 : C2;

    __shared__ unsigned short As[128 * 64];      // [row][k] 128-B rows
    __shared__ unsigned short Bs[BN * 64];

    const int tid  = threadIdx.x;
    const int lane = tid & 63;
    const int w    = tid >> 6;
    const int wr   = w >> 1, wc = w & 1;
    const int fr   = lane & 15, kg = lane >> 4;
    const int m0   = blockIdx.x * 128, n0 = blockIdx.y * BN;

    const int srow8 = lane >> 3;                       // 0..7
    const int sswz  = ((lane & 7) ^ (lane >> 3)) * 8;  // pre-swizzled k-offset

    f32x4 acc[4][NJ] = {};

    for (int t = 0; t < K / 64; ++t) {
        const int k0 = t * 64;
        #pragma unroll
        for (int it = 0; it < 4; ++it) {
            const int c = w * 4 + it;
            gload16(&A[(size_t)(m0 + c * 8 + srow8) * K + k0 + sswz], &As[c * 512]);
            if (BN == 128)
                gload16(&Bt[(size_t)(n0 + c * 8 + srow8) * K + k0 + sswz], &Bs[c * 512]);
        }
        if (BN == 64) {
            #pragma unroll
            for (int it = 0; it < 2; ++it) {
                const int c = w * 2 + it;    // 8 chunks cover 64 rows
                gload16(&Bt[(size_t)(n0 + c * 8 + srow8) * K + k0 + sswz], &Bs[c * 512]);
            }
        }
        __syncthreads();

        const int rsw = (fr & 7) << 4;   // read-side XOR (byte)
        #pragma unroll
        for (int kh = 0; kh < 2; ++kh) {
            bf16x8 af[4], bfj[NJ];
            #pragma unroll
            for (int i = 0; i < 4; ++i)
                af[i] = *reinterpret_cast<const bf16x8*>(
                    reinterpret_cast<const char*>(As) +
                    (wr * 64 + i * 16 + fr) * 128 + ((kh * 64 + kg * 16) ^ rsw));
            #pragma unroll
            for (int j = 0; j < NJ; ++j)
                bfj[j] = *reinterpret_cast<const bf16x8*>(
                    reinterpret_cast<const char*>(Bs) +
                    (wc * (BN / 2) + j * 16 + fr) * 128 + ((kh * 64 + kg * 16) ^ rsw));
            #pragma unroll
            for (int i = 0; i < 4; ++i)
                #pragma unroll
                for (int j = 0; j < NJ; ++j)
                    acc[i][j] = mfma_16x16x32_bf16(af[i], bfj[j], acc[i][j]);
        }
        __syncthreads();
    }

    if (MODE == 1 && z == 2) {
        // V: store transposed per batch: vt[(bb*1024 + n)*2048 + s]
        unsigned short* vt = reinterpret_cast<unsigned short*>(C);
        #pragma unroll
        for (int i = 0; i < 4; ++i) {
            const int m = m0 + wr * 64 + i * 16 + kg * 4;
            const int bb = m >> 11, s = m & 2047;
            #pragma unroll
            for (int j = 0; j < NJ; ++j) {
                const int n = n0 + wc * (BN / 2) + j * 16 + fr;
                const float bv = bias[n];
                uint2 pk;
                pk.x = cvt_pk_bf16(acc[i][j][0] + bv, acc[i][j][1] + bv);
                pk.y = cvt_pk_bf16(acc[i][j][2] + bv, acc[i][j][3] + bv);
                *reinterpret_cast<uint2*>(&vt[((size_t)(bb * 1024 + n)) * 2048 + s]) = pk;
            }
        }
    } else if (MODE == 1) {
        // z==0 (Q): fold 1/sqrt(64) * log2(e) so attention uses native exp2.
        const float sc = (z == 0) ? 0.125f * 1.44269504088896340736f : 1.0f;
        unsigned short* Cb = reinterpret_cast<unsigned short*>(C);
        #pragma unroll
        for (int i = 0; i < 4; ++i) {
            const int m = m0 + wr * 64 + i * 16 + kg * 4;
            #pragma unroll
            for (int j = 0; j < NJ; ++j) {
                const int n = n0 + wc * (BN / 2) + j * 16 + fr;
                const float bv = bias[n];
                const unsigned int p0 = cvt_pk_bf16((acc[i][j][0] + bv) * sc, (acc[i][j][1] + bv) * sc);
                const unsigned int p1 = cvt_pk_bf16((acc[i][j][2] + bv) * sc, (acc[i][j][3] + bv) * sc);
                Cb[(size_t)(m + 0) * N + n] = (unsigned short)p0;
                Cb[(size_t)(m + 1) * N + n] = (unsigned short)(p0 >> 16);
                Cb[(size_t)(m + 2) * N + n] = (unsigned short)p1;
                Cb[(size_t)(m + 3) * N + n] = (unsigned short)(p1 >> 16);
            }
        }
    } else {
        float* Cf = reinterpret_cast<float*>(C);
        #pragma unroll
        for (int i = 0; i < 4; ++i) {
            const int m = m0 + wr * 64 + i * 16 + kg * 4;
            #pragma unroll
            for (int j = 0; j < NJ; ++j) {
                const int n = n0 + wc * (BN / 2) + j * 16 + fr;
                const float bv = bias[n];
                #pragma unroll
                for (int r = 0; r < 4; ++r)
                    Cf[(size_t)(m + r) * N + n] = acc[i][j][r] + bv;
            }
        }
    }
}

// ---------------------------------------------------------------------------
// V tail suffix sums (unchanged).
// ---------------------------------------------------------------------------
__global__ __launch_bounds__(256) void k_vtail(
    const unsigned short* __restrict__ vt, float* __restrict__ vtail)
{
    const int row = blockIdx.x * 4 + (threadIdx.x >> 6);
    const int l = threadIdx.x & 63;
    const unsigned short* p = &vt[(size_t)row * 2048 + l * 32];
    float s = 0.f;
    #pragma unroll
    for (int i = 0; i < 4; ++i) {
        ushortx8 v = *reinterpret_cast<const ushortx8*>(&p[i * 8]);
        #pragma unroll
        for (int e = 0; e < 8; ++e)
            s += __builtin_bit_cast(float, (unsigned int)v[e] << 16);
    }
    #pragma unroll
    for (int off = 1; off < 64; off <<= 1) {
        const float t = __shfl_down(s, off, 64);
        s += (l + off < 64) ? t : 0.f;
    }
    float tv = __shfl(s, (2 * l + 2) & 63, 64);
    if (l == 31) tv = 0.f;
    if (l < 32) vtail[(size_t)row * 32 + l] = tv;
}

// ---------------------------------------------------------------------------
// Attention (round-18 proven, best known): KVBLK=64, causal pair balancing,
// XCD chunked swizzle, dbuf swizzled LDS, T14 prefetch, T5 setprio, exp2
// path, ones-column MFMA row-sum denominator.
// ---------------------------------------------------------------------------
template <bool MASK>
DI void attn_tile(const unsigned char* KsB, const unsigned char* VtsB,
                  unsigned char* PB, bf16x8 qf0, bf16x8 qf1,
                  f32x4 (&o)[4], f32x4& oS, int w, int fr, int kg)
{
    const int sw = (fr & 7) << 4;
    #pragma unroll
    for (int j = 0; j < 4; ++j) {
        const int row = j * 16 + fr;
        const bf16x8 kf0 = *reinterpret_cast<const bf16x8*>(KsB + row * 128 + ((kg * 16) ^ sw));
        const bf16x8 kf1 = *reinterpret_cast<const bf16x8*>(KsB + row * 128 + ((64 + kg * 16) ^ sw));
        f32x4 s = {0.f, 0.f, 0.f, 0.f};
        __builtin_amdgcn_s_setprio(1);
        s = mfma_16x16x32_bf16(kf0, qf0, s);   // swapped: A=K rows (keys), B=Q
        s = mfma_16x16x32_bf16(kf1, qf1, s);
        __builtin_amdgcn_s_setprio(0);
        float p[4];
        #pragma unroll
        for (int r = 0; r < 4; ++r) {
            float e = exp2f(s[r]);             // q pre-scaled by log2e -> native 2^x
            if (MASK && (j * 16 + kg * 4 + r > w * 16 + fr)) e = 1.0f;  // exp(-1e-8)==1.0f
            p[r] = e;
        }
        uint2 pk;
        pk.x = cvt_pk_bf16(p[0], p[1]);
        pk.y = cvt_pk_bf16(p[2], p[3]);
        *reinterpret_cast<uint2*>(PB + fr * 128 + ((j * 32 + kg * 8) ^ sw)) = pk;
    }
    // all-ones B fragment (bf16 1.0 broadcast) for the P row-sum MFMA
    bf16x8 ones;
    #pragma unroll
    for (int b = 0; b < 8; ++b) ones[b] = (__bf16)1.0f;
    __builtin_amdgcn_s_setprio(1);
    #pragma unroll
    for (int kk = 0; kk < 2; ++kk) {
        const bf16x8 pf = *reinterpret_cast<const bf16x8*>(PB + fr * 128 + ((kk * 64 + kg * 16) ^ sw));
        #pragma unroll
        for (int n = 0; n < 4; ++n) {
            const int vrow = n * 16 + fr;
            const bf16x8 vf = *reinterpret_cast<const bf16x8*>(VtsB + vrow * 128 + ((kk * 64 + kg * 16) ^ sw));
            o[n] = mfma_16x16x32_bf16(pf, vf, o[n]);
        }
        oS = mfma_16x16x32_bf16(pf, ones, oS);   // denominator via matrix pipe
    }
    __builtin_amdgcn_s_setprio(0);
}

DI void attn_sweep(int qt,
                   const unsigned short* __restrict__ qp,
                   const unsigned short* __restrict__ kp,
                   const unsigned short* __restrict__ vt,
                   const float* __restrict__ vtail,
                   unsigned short* __restrict__ ctx,
                   unsigned char (*KsB)[64 * 128], unsigned char (*VtsB)[64 * 128],
                   unsigned char* PB, size_t baseQ, size_t baseV, int b, int h,
                   int w, int fr, int kg, int sr, int sc8, int wb0, int wb1)
{
    constexpr int S = 2048, D = 1024;
    const int q0 = qt * 64 + w * 16;

    bf16x8 qf0, qf1;
    {
        const size_t roff = baseQ + (size_t)(q0 + fr) * D;
        qf0 = *reinterpret_cast<const bf16x8*>(&qp[roff + kg * 8]);
        qf1 = *reinterpret_cast<const bf16x8*>(&qp[roff + 32 + kg * 8]);
    }

    f32x4 o[4] = {};
    f32x4 oS = {};
    const int NT = qt + 1;

    // prologue: stage tile 0 into buffer 0
    {
        const ushortx8 kr0 = *reinterpret_cast<const ushortx8*>(&kp[baseQ + (size_t)sr * D + sc8]);
        const ushortx8 kr1 = *reinterpret_cast<const ushortx8*>(&kp[baseQ + (size_t)(sr + 32) * D + sc8]);
        const ushortx8 vr0 = *reinterpret_cast<const ushortx8*>(&vt[baseV + (size_t)sr * S + sc8]);
        const ushortx8 vr1 = *reinterpret_cast<const ushortx8*>(&vt[baseV + (size_t)(sr + 32) * S + sc8]);
        *reinterpret_cast<ushortx8*>(KsB[0] + wb0)  = kr0;
        *reinterpret_cast<ushortx8*>(KsB[0] + wb1)  = kr1;
        *reinterpret_cast<ushortx8*>(VtsB[0] + wb0) = vr0;
        *reinterpret_cast<ushortx8*>(VtsB[0] + wb1) = vr1;
    }
    __syncthreads();

    for (int t = 0; t < NT; ++t) {
        const int cur = t & 1;
        const bool more = (t + 1 < NT);
        ushortx8 nk0, nk1, nv0, nv1;
        if (more) {   // T14: issue next-tile loads before compute
            const int kt1 = (t + 1) * 64;
            nk0 = *reinterpret_cast<const ushortx8*>(&kp[baseQ + (size_t)(kt1 + sr) * D + sc8]);
            nk1 = *reinterpret_cast<const ushortx8*>(&kp[baseQ + (size_t)(kt1 + sr + 32) * D + sc8]);
            nv0 = *reinterpret_cast<const ushortx8*>(&vt[baseV + (size_t)sr * S + kt1 + sc8]);
            nv1 = *reinterpret_cast<const ushortx8*>(&vt[baseV + (size_t)(sr + 32) * S + kt1 + sc8]);
        }
        if (more)
            attn_tile<false>(KsB[cur], VtsB[cur], PB, qf0, qf1, o, oS, w, fr, kg);
        else
            attn_tile<true>(KsB[cur], VtsB[cur], PB, qf0, qf1, o, oS, w, fr, kg);
        if (more) {   // write next tile into the other buffer (no extra barrier)
            const int nxt = cur ^ 1;
            *reinterpret_cast<ushortx8*>(KsB[nxt] + wb0)  = nk0;
            *reinterpret_cast<ushortx8*>(KsB[nxt] + wb1)  = nk1;
            *reinterpret_cast<ushortx8*>(VtsB[nxt] + wb0) = nv0;
            *reinterpret_cast<ushortx8*>(VtsB[nxt] + wb1) = nv1;
        }
        __syncthreads();
    }

    // denominator: oS[r] already holds q-row (q0 + kg*4 + r)'s P-sum; add
    // analytic tail count, reciprocal once.
    const float tailc = (float)(S - (qt + 1) * 64);
    float rlq[4];
    #pragma unroll
    for (int r = 0; r < 4; ++r) rlq[r] = 1.0f / (oS[r] + tailc);

    float tl[4];
    #pragma unroll
    for (int n = 0; n < 4; ++n)
        tl[n] = vtail[((size_t)(b * 1024) + h * 64 + n * 16 + fr) * 32 + qt];

    #pragma unroll
    for (int n = 0; n < 4; ++n)
        #pragma unroll
        for (int r = 0; r < 4; ++r) {
            const int qrow = q0 + kg * 4 + r;
            ctx[baseQ + (size_t)qrow * D + n * 16 + fr] = f2bf((o[n][r] + tl[n]) * rlq[r]);
        }
}

__global__ __launch_bounds__(256, 2) void k_attn(
    const unsigned short* __restrict__ qp,
    const unsigned short* __restrict__ kp,
    const unsigned short* __restrict__ vt,
    const float* __restrict__ vtail,
    unsigned short* __restrict__ ctx)
{
    constexpr int S = 2048, D = 1024;
    // T1 chunked XCD swizzle: G = (L%8)*64 + L/8 (bijective, 512 = 8*64):
    // each XCD's 64 resident blocks = 4 complete (h,b) panel groups (2 MB).
    const int L = blockIdx.x;
    const int G = (L & 7) * 64 + (L >> 3);
    const int p = G & 15;            // pair index 0..15
    const int h = (G >> 4) & 15;     // head
    const int b = G >> 8;            // batch

    __shared__ alignas(16) unsigned char KsB[2][64 * 128];     // dbuf K, swizzled
    __shared__ alignas(16) unsigned char VtsB[2][64 * 128];    // dbuf V, swizzled
    __shared__ alignas(16) unsigned char PlsB[4 * 16 * 128];   // per-wave P

    const int tid  = threadIdx.x;
    const int lane = tid & 63, w = tid >> 6;
    const int fr   = lane & 15, kg = lane >> 4;
    unsigned char* PB = PlsB + w * 2048;

    const size_t baseQ = ((size_t)b * S) * D + (size_t)h * 64;
    const size_t baseV = ((size_t)b * D + (size_t)h * 64) * S;

    const int sr  = tid >> 3;          // staging row 0..31
    const int sc8 = (tid & 7) * 8;     // element offset (8 bf16)
    const int wb0 = sr * 128 + (((tid & 7) * 16) ^ ((sr & 7) << 4));
    const int wb1 = (sr + 32) * 128 + (((tid & 7) * 16) ^ (((sr + 32) & 7) << 4));

    // pair (31-p, p): total key-tiles = (32-p) + (p+1) = 33, uniform
    attn_sweep(31 - p, qp, kp, vt, vtail, ctx, KsB, VtsB, PB,
               baseQ, baseV, b, h, w, fr, kg, sr, sc8, wb0, wb1);
    attn_sweep(p, qp, kp, vt, vtail, ctx, KsB, VtsB, PB,
               baseQ, baseV, b, h, w, fr, kg, sr, sc8, wb0, wb1);
}

// ---------------------------------------------------------------------------
extern "C" void kernel_launch(void* const* d_in, const int* in_sizes, int n_in,
                              void* d_out, int out_size, void* d_ws, size_t ws_size,
                              hipStream_t stream) {
    constexpr int B = 2, S = 2048, D = 1024;
    constexpr int M = B * S;                 // 4096
    constexpr size_t MD = (size_t)M * D;     // 4M elements

    const float* Q  = (const float*)d_in[0];
    const float* K  = (const float*)d_in[1];
    const float* V  = (const float*)d_in[2];
    const float* Wq = (const float*)d_in[4];
    const float* bq = (const float*)d_in[5];
    const float* Wk = (const float*)d_in[6];
    const float* bk = (const float*)d_in[7];
    const float* Wv = (const float*)d_in[8];
    const float* bv = (const float*)d_in[9];
    const float* Wo = (const float*)d_in[10];
    const float* bo = (const float*)d_in[11];

    // d_out (16 MiB, dead until final GEMM): qc (8 MiB) + kc (8 MiB)
    unsigned short* qc = (unsigned short*)d_out;
    unsigned short* kc = qc + MD;
    // d_ws (40 MiB): qb, kb, vtg, vc/ctx (8 MiB each) + Wto/Wtq/Wtk/Wtv (2 MiB each)
    char* ws = (char*)d_ws;
    unsigned short* qb  = (unsigned short*)(ws);
    unsigned short* kb  = (unsigned short*)(ws + (8u << 20));
    unsigned short* vtg = (unsigned short*)(ws + (16u << 20));
    unsigned short* vc  = (unsigned short*)(ws + (24u << 20));
    unsigned short* Wto = (unsigned short*)(ws + (32u << 20));
    unsigned short* Wtq = (unsigned short*)(ws + (34u << 20));
    unsigned short* Wtk = (unsigned short*)(ws + (36u << 20));
    unsigned short* Wtv = (unsigned short*)(ws + (38u << 20));
    unsigned short* ctx = vc;                       // aliases vc (dead by then)
    float* vtail        = (float*)Wtq;              // aliases Wtq (dead by then)

    dim3 blk(256);
    k_prep<<<dim3(4096), blk, 0, stream>>>(
        Q, K, V, qc, kc, vc, Wq, Wk, Wv, Wo, Wtq, Wtk, Wtv, Wto);
    k_gemm_bf16<1, 64><<<dim3(M / 128, D / 64, 3), blk, 0, stream>>>(
        qc, kc, vc, Wtq, Wtk, Wtv, bq, bk, bv, qb, kb, vtg);
    k_vtail<<<dim3((B * D) / 4), blk, 0, stream>>>(vtg, vtail);
    k_attn<<<dim3(512), blk, 0, stream>>>(qb, kb, vtg, vtail, ctx);
    k_gemm_bf16<0, 64><<<dim3(M / 128, D / 64, 1), blk, 0, stream>>>(
        ctx, ctx, ctx, Wto, Wto, Wto, bo, bo, bo, d_out, d_out, d_out);
}

// Round 20
// 117.756 us; speedup vs baseline: 1.1558x; 1.0339x over previous
//
#include <hip/hip_runtime.h>
#include <hip/hip_bf16.h>
#include <stdint.h>
#include <math.h>

#define DI __device__ __forceinline__

typedef __bf16 bf16x8 __attribute__((ext_vector_type(8)));
typedef float f32x4 __attribute__((ext_vector_type(4)));
typedef unsigned short ushortx8 __attribute__((ext_vector_type(8)));

// fp32 -> bf16 round-to-nearest-even (scalar path)
DI unsigned short f2bf(float f) {
    unsigned int u = __builtin_bit_cast(unsigned int, f);
    u += 0x7fffu + ((u >> 16) & 1u);
    return (unsigned short)(u >> 16);
}

// packed fp32x2 -> bf16x2 (1 VALU op). lo -> bits 0-15, hi -> bits 16-31.
DI unsigned int cvt_pk_bf16(float lo, float hi) {
    unsigned int r;
    asm("v_cvt_pk_bf16_f32 %0, %1, %2" : "=v"(r) : "v"(lo), "v"(hi));
    return r;
}

DI f32x4 mfma_16x16x32_bf16(bf16x8 a, bf16x8 b, f32x4 c) {
    return __builtin_amdgcn_mfma_f32_16x16x32_bf16(a, b, c, 0, 0, 0);
}

// async global->LDS, 16B per lane. LDS dest: wave-uniform base + lane*16.
DI void gload16(const unsigned short* g, unsigned short* l) {
    __builtin_amdgcn_global_load_lds(
        (const __attribute__((address_space(1))) void*)g,
        (__attribute__((address_space(3))) void*)l, 16, 0, 0);
}

// ---------------------------------------------------------------------------
// k_prep: fused prep (proven). Blocks 0..3071: fp32->bf16 cvt of Q/K/V.
// Blocks 3072..4095: W -> Wt bf16 transpose (4 matrices, 64x64 tiles).
// ---------------------------------------------------------------------------
__global__ __launch_bounds__(256) void k_prep(
    const float* __restrict__ Q, const float* __restrict__ K, const float* __restrict__ V,
    unsigned short* __restrict__ qc, unsigned short* __restrict__ kc, unsigned short* __restrict__ vc,
    const float* __restrict__ w0, const float* __restrict__ w1,
    const float* __restrict__ w2, const float* __restrict__ w3,
    unsigned short* __restrict__ o0, unsigned short* __restrict__ o1,
    unsigned short* __restrict__ o2, unsigned short* __restrict__ o3)
{
    constexpr int N = 1024;
    __shared__ unsigned short L[64 * 64];
    const int bx = blockIdx.x;
    const int tid = threadIdx.x;

    if (bx < 3072) {
        const int z = bx >> 10;
        const int ib = bx & 1023;
        const float* s = z == 0 ? Q : z == 1 ? K : V;
        unsigned short* d = z == 0 ? qc : z == 1 ? kc : vc;
        const int i0 = ib * 256 + tid;
        #pragma unroll
        for (int it = 0; it < 4; ++it) {
            const int i = i0 + it * 262144;
            const float4 v = reinterpret_cast<const float4*>(s)[i];
            uint2 pk;
            pk.x = cvt_pk_bf16(v.x, v.y);
            pk.y = cvt_pk_bf16(v.z, v.w);
            reinterpret_cast<uint2*>(d)[i] = pk;
        }
    } else {
        const int r4 = bx - 3072;
        const int z = r4 >> 8;
        const int tile = r4 & 255;
        const float* W = z == 0 ? w0 : z == 1 ? w1 : z == 2 ? w2 : w3;
        unsigned short* O = z == 0 ? o0 : z == 1 ? o1 : z == 2 ? o2 : o3;
        const int k0 = (tile >> 4) * 64, n0 = (tile & 15) * 64;

        const int r = tid >> 2, cbase = (tid & 3) * 16;
        #pragma unroll
        for (int i = 0; i < 4; ++i) {
            const int c = cbase + i * 4;
            const float4 v = *reinterpret_cast<const float4*>(&W[(size_t)(k0 + r) * N + n0 + c]);
            uint2 pk;
            pk.x = cvt_pk_bf16(v.x, v.y);
            pk.y = cvt_pk_bf16(v.z, v.w);
            const int byte = r * 128 + ((c * 2) ^ ((r & 7) << 4));
            *reinterpret_cast<uint2*>(reinterpret_cast<char*>(L) + byte) = pk;
        }
        __syncthreads();

        const int n = tid >> 2, kc2 = (tid & 3) * 16;
        ushortx8 v0, v1;
        #pragma unroll
        for (int j = 0; j < 8; ++j) {
            const int ka = kc2 + j, kb2 = kc2 + 8 + j;
            v0[j] = *reinterpret_cast<const unsigned short*>(
                reinterpret_cast<const char*>(L) + ka * 128 + ((n * 2) ^ ((ka & 7) << 4)));
            v1[j] = *reinterpret_cast<const unsigned short*>(
                reinterpret_cast<const char*>(L) + kb2 * 128 + ((n * 2) ^ ((kb2 & 7) << 4)));
        }
        unsigned short* op = &O[(size_t)(n0 + n) * N + k0 + kc2];
        *reinterpret_cast<ushortx8*>(op) = v0;
        *reinterpret_cast<ushortx8*>(op + 8) = v1;
    }
}

// ---------------------------------------------------------------------------
// bf16 GEMM, BK=64, both-sides swizzle (proven; conflicts = 0). BN=64 both.
// ---------------------------------------------------------------------------
template <int MODE, int BN>
__global__ __launch_bounds__(256) void k_gemm_bf16(
    const unsigned short* __restrict__ A0, const unsigned short* __restrict__ A1,
    const unsigned short* __restrict__ A2,
    const unsigned short* __restrict__ B0, const unsigned short* __restrict__ B1,
    const unsigned short* __restrict__ B2,
    const float* __restrict__ bias0, const float* __restrict__ bias1,
    const float* __restrict__ bias2,
    void* C0, void* C1, void* C2)
{
    constexpr int K = 1024, N = 1024;
    constexpr int NJ = BN / 32;          // wave-col fragments
    const int z = MODE ? blockIdx.z : 0;
    const unsigned short* A  = z == 0 ? A0 : z == 1 ? A1 : A2;
    const unsigned short* Bt = z == 0 ? B0 : z == 1 ? B1 : B2;
    const float* bias        = z == 0 ? bias0 : z == 1 ? bias1 : bias2;
    void* C                  = z == 0 ? C0 : z == 1 ? C1 : C2;

    __shared__ unsigned short As[128 * 64];      // [row][k] 128-B rows
    __shared__ unsigned short Bs[BN * 64];

    const int tid  = threadIdx.x;
    const int lane = tid & 63;
    const int w    = tid >> 6;
    const int wr   = w >> 1, wc = w & 1;
    const int fr   = lane & 15, kg = lane >> 4;
    const int m0   = blockIdx.x * 128, n0 = blockIdx.y * BN;

    const int srow8 = lane >> 3;                       // 0..7
    const int sswz  = ((lane & 7) ^ (lane >> 3)) * 8;  // pre-swizzled k-offset

    f32x4 acc[4][NJ] = {};

    for (int t = 0; t < K / 64; ++t) {
        const int k0 = t * 64;
        #pragma unroll
        for (int it = 0; it < 4; ++it) {
            const int c = w * 4 + it;
            gload16(&A[(size_t)(m0 + c * 8 + srow8) * K + k0 + sswz], &As[c * 512]);
            if (BN == 128)
                gload16(&Bt[(size_t)(n0 + c * 8 + srow8) * K + k0 + sswz], &Bs[c * 512]);
        }
        if (BN == 64) {
            #pragma unroll
            for (int it = 0; it < 2; ++it) {
                const int c = w * 2 + it;    // 8 chunks cover 64 rows
                gload16(&Bt[(size_t)(n0 + c * 8 + srow8) * K + k0 + sswz], &Bs[c * 512]);
            }
        }
        __syncthreads();

        const int rsw = (fr & 7) << 4;   // read-side XOR (byte)
        #pragma unroll
        for (int kh = 0; kh < 2; ++kh) {
            bf16x8 af[4], bfj[NJ];
            #pragma unroll
            for (int i = 0; i < 4; ++i)
                af[i] = *reinterpret_cast<const bf16x8*>(
                    reinterpret_cast<const char*>(As) +
                    (wr * 64 + i * 16 + fr) * 128 + ((kh * 64 + kg * 16) ^ rsw));
            #pragma unroll
            for (int j = 0; j < NJ; ++j)
                bfj[j] = *reinterpret_cast<const bf16x8*>(
                    reinterpret_cast<const char*>(Bs) +
                    (wc * (BN / 2) + j * 16 + fr) * 128 + ((kh * 64 + kg * 16) ^ rsw));
            #pragma unroll
            for (int i = 0; i < 4; ++i)
                #pragma unroll
                for (int j = 0; j < NJ; ++j)
                    acc[i][j] = mfma_16x16x32_bf16(af[i], bfj[j], acc[i][j]);
        }
        __syncthreads();
    }

    if (MODE == 1 && z == 2) {
        // V: store transposed per batch: vt[(bb*1024 + n)*2048 + s]
        unsigned short* vt = reinterpret_cast<unsigned short*>(C);
        #pragma unroll
        for (int i = 0; i < 4; ++i) {
            const int m = m0 + wr * 64 + i * 16 + kg * 4;
            const int bb = m >> 11, s = m & 2047;
            #pragma unroll
            for (int j = 0; j < NJ; ++j) {
                const int n = n0 + wc * (BN / 2) + j * 16 + fr;
                const float bv = bias[n];
                uint2 pk;
                pk.x = cvt_pk_bf16(acc[i][j][0] + bv, acc[i][j][1] + bv);
                pk.y = cvt_pk_bf16(acc[i][j][2] + bv, acc[i][j][3] + bv);
                *reinterpret_cast<uint2*>(&vt[((size_t)(bb * 1024 + n)) * 2048 + s]) = pk;
            }
        }
    } else if (MODE == 1) {
        // z==0 (Q): fold 1/sqrt(64) * log2(e) so attention uses native exp2.
        const float sc = (z == 0) ? 0.125f * 1.44269504088896340736f : 1.0f;
        unsigned short* Cb = reinterpret_cast<unsigned short*>(C);
        #pragma unroll
        for (int i = 0; i < 4; ++i) {
            const int m = m0 + wr * 64 + i * 16 + kg * 4;
            #pragma unroll
            for (int j = 0; j < NJ; ++j) {
                const int n = n0 + wc * (BN / 2) + j * 16 + fr;
                const float bv = bias[n];
                const unsigned int p0 = cvt_pk_bf16((acc[i][j][0] + bv) * sc, (acc[i][j][1] + bv) * sc);
                const unsigned int p1 = cvt_pk_bf16((acc[i][j][2] + bv) * sc, (acc[i][j][3] + bv) * sc);
                Cb[(size_t)(m + 0) * N + n] = (unsigned short)p0;
                Cb[(size_t)(m + 1) * N + n] = (unsigned short)(p0 >> 16);
                Cb[(size_t)(m + 2) * N + n] = (unsigned short)p1;
                Cb[(size_t)(m + 3) * N + n] = (unsigned short)(p1 >> 16);
            }
        }
    } else {
        float* Cf = reinterpret_cast<float*>(C);
        #pragma unroll
        for (int i = 0; i < 4; ++i) {
            const int m = m0 + wr * 64 + i * 16 + kg * 4;
            #pragma unroll
            for (int j = 0; j < NJ; ++j) {
                const int n = n0 + wc * (BN / 2) + j * 16 + fr;
                const float bv = bias[n];
                #pragma unroll
                for (int r = 0; r < 4; ++r)
                    Cf[(size_t)(m + r) * N + n] = acc[i][j][r] + bv;
            }
        }
    }
}

// ---------------------------------------------------------------------------
// V tail suffix sums (unchanged).
// ---------------------------------------------------------------------------
__global__ __launch_bounds__(256) void k_vtail(
    const unsigned short* __restrict__ vt, float* __restrict__ vtail)
{
    const int row = blockIdx.x * 4 + (threadIdx.x >> 6);
    const int l = threadIdx.x & 63;
    const unsigned short* p = &vt[(size_t)row * 2048 + l * 32];
    float s = 0.f;
    #pragma unroll
    for (int i = 0; i < 4; ++i) {
        ushortx8 v = *reinterpret_cast<const ushortx8*>(&p[i * 8]);
        #pragma unroll
        for (int e = 0; e < 8; ++e)
            s += __builtin_bit_cast(float, (unsigned int)v[e] << 16);
    }
    #pragma unroll
    for (int off = 1; off < 64; off <<= 1) {
        const float t = __shfl_down(s, off, 64);
        s += (l + off < 64) ? t : 0.f;
    }
    float tv = __shfl(s, (2 * l + 2) & 63, 64);
    if (l == 31) tv = 0.f;
    if (l < 32) vtail[(size_t)row * 32 + l] = tv;
}

// ---------------------------------------------------------------------------
// Attention v10: K/V staging via global_load_lds with PRE-SWIZZLED SOURCE
// (sswz = ((lane&7)^(lane>>3))*8 -- per-lane constant because the LDS-row
// swizzle key row&7 == lane>>3) + LINEAR LDS dest; reads keep their XOR.
// Same involution as the proven GEMM (rule #21 both-sides pattern). Deletes
// the reg-staging round-trip (4 loads + 4 ds_writes per thread per tile).
// exp2 via __builtin_amdgcn_exp2f (bare v_exp_f32). Rest = round-18 proven.
// ---------------------------------------------------------------------------
template <bool MASK>
DI void attn_tile(const unsigned char* KsB, const unsigned char* VtsB,
                  unsigned char* PB, bf16x8 qf0, bf16x8 qf1,
                  f32x4 (&o)[4], f32x4& oS, int w, int fr, int kg)
{
    const int sw = (fr & 7) << 4;
    #pragma unroll
    for (int j = 0; j < 4; ++j) {
        const int row = j * 16 + fr;
        const bf16x8 kf0 = *reinterpret_cast<const bf16x8*>(KsB + row * 128 + ((kg * 16) ^ sw));
        const bf16x8 kf1 = *reinterpret_cast<const bf16x8*>(KsB + row * 128 + ((64 + kg * 16) ^ sw));
        f32x4 s = {0.f, 0.f, 0.f, 0.f};
        __builtin_amdgcn_s_setprio(1);
        s = mfma_16x16x32_bf16(kf0, qf0, s);   // swapped: A=K rows (keys), B=Q
        s = mfma_16x16x32_bf16(kf1, qf1, s);
        __builtin_amdgcn_s_setprio(0);
        float p[4];
        #pragma unroll
        for (int r = 0; r < 4; ++r) {
            float e = __builtin_amdgcn_exp2f(s[r]);   // q pre-scaled by log2e
            if (MASK && (j * 16 + kg * 4 + r > w * 16 + fr)) e = 1.0f;  // exp(-1e-8)==1.0f
            p[r] = e;
        }
        uint2 pk;
        pk.x = cvt_pk_bf16(p[0], p[1]);
        pk.y = cvt_pk_bf16(p[2], p[3]);
        *reinterpret_cast<uint2*>(PB + fr * 128 + ((j * 32 + kg * 8) ^ sw)) = pk;
    }
    // all-ones B fragment (bf16 1.0 broadcast) for the P row-sum MFMA
    bf16x8 ones;
    #pragma unroll
    for (int b = 0; b < 8; ++b) ones[b] = (__bf16)1.0f;
    __builtin_amdgcn_s_setprio(1);
    #pragma unroll
    for (int kk = 0; kk < 2; ++kk) {
        const bf16x8 pf = *reinterpret_cast<const bf16x8*>(PB + fr * 128 + ((kk * 64 + kg * 16) ^ sw));
        #pragma unroll
        for (int n = 0; n < 4; ++n) {
            const int vrow = n * 16 + fr;
            const bf16x8 vf = *reinterpret_cast<const bf16x8*>(VtsB + vrow * 128 + ((kk * 64 + kg * 16) ^ sw));
            o[n] = mfma_16x16x32_bf16(pf, vf, o[n]);
        }
        oS = mfma_16x16x32_bf16(pf, ones, oS);   // denominator via matrix pipe
    }
    __builtin_amdgcn_s_setprio(0);
}

DI void attn_sweep(int qt,
                   const unsigned short* __restrict__ qp,
                   const unsigned short* __restrict__ kp,
                   const unsigned short* __restrict__ vt,
                   const float* __restrict__ vtail,
                   unsigned short* __restrict__ ctx,
                   unsigned char (*KsB)[64 * 128], unsigned char (*VtsB)[64 * 128],
                   unsigned char* PB, size_t baseQ, size_t baseV, int b, int h,
                   int lane, int w, int fr, int kg)
{
    constexpr int S = 2048, D = 1024;
    const int q0 = qt * 64 + w * 16;

    bf16x8 qf0, qf1;
    {
        const size_t roff = baseQ + (size_t)(q0 + fr) * D;
        qf0 = *reinterpret_cast<const bf16x8*>(&qp[roff + kg * 8]);
        qf1 = *reinterpret_cast<const bf16x8*>(&qp[roff + 32 + kg * 8]);
    }

    f32x4 o[4] = {};
    f32x4 oS = {};
    const int NT = qt + 1;

    // staging constants: 8 chunks of 1 KB (8 rows x 128 B); wave w owns
    // chunks {2w, 2w+1}; lane covers row c*8+(lane>>3) at pre-swizzled col.
    const int srow = lane >> 3;                 // 0..7
    const int sswz = ((lane & 7) ^ srow) * 8;   // element offset (involution)
    const int c0   = w * 2;

    // prologue: DMA tile 0 into buffer 0
    #pragma unroll
    for (int i = 0; i < 2; ++i) {
        const int c = c0 + i;
        const int row = c * 8 + srow;
        gload16(&kp[baseQ + (size_t)row * D + sswz],
                reinterpret_cast<unsigned short*>(KsB[0] + c * 1024));
        gload16(&vt[baseV + (size_t)row * S + sswz],
                reinterpret_cast<unsigned short*>(VtsB[0] + c * 1024));
    }
    __syncthreads();

    for (int t = 0; t < NT; ++t) {
        const int cur = t & 1;
        if (t + 1 < NT) {   // issue next-tile DMA first; in flight across compute
            const int kt1 = (t + 1) * 64;
            #pragma unroll
            for (int i = 0; i < 2; ++i) {
                const int c = c0 + i;
                const int row = c * 8 + srow;
                gload16(&kp[baseQ + (size_t)(kt1 + row) * D + sswz],
                        reinterpret_cast<unsigned short*>(KsB[cur ^ 1] + c * 1024));
                gload16(&vt[baseV + (size_t)row * S + kt1 + sswz],
                        reinterpret_cast<unsigned short*>(VtsB[cur ^ 1] + c * 1024));
            }
        }
        if (t == NT - 1)
            attn_tile<true>(KsB[cur], VtsB[cur], PB, qf0, qf1, o, oS, w, fr, kg);
        else
            attn_tile<false>(KsB[cur], VtsB[cur], PB, qf0, qf1, o, oS, w, fr, kg);
        __syncthreads();   // drains vmcnt: buf[cur^1] ready, buf[cur] reusable
    }

    // denominator: oS[r] holds q-row (q0 + kg*4 + r)'s P-sum; add tail count.
    const float tailc = (float)(S - (qt + 1) * 64);
    float rlq[4];
    #pragma unroll
    for (int r = 0; r < 4; ++r) rlq[r] = 1.0f / (oS[r] + tailc);

    float tl[4];
    #pragma unroll
    for (int n = 0; n < 4; ++n)
        tl[n] = vtail[((size_t)(b * 1024) + h * 64 + n * 16 + fr) * 32 + qt];

    #pragma unroll
    for (int n = 0; n < 4; ++n)
        #pragma unroll
        for (int r = 0; r < 4; ++r) {
            const int qrow = q0 + kg * 4 + r;
            ctx[baseQ + (size_t)qrow * D + n * 16 + fr] = f2bf((o[n][r] + tl[n]) * rlq[r]);
        }
}

__global__ __launch_bounds__(256, 2) void k_attn(
    const unsigned short* __restrict__ qp,
    const unsigned short* __restrict__ kp,
    const unsigned short* __restrict__ vt,
    const float* __restrict__ vtail,
    unsigned short* __restrict__ ctx)
{
    constexpr int S = 2048, D = 1024;
    // T1 chunked XCD swizzle: G = (L%8)*64 + L/8 (bijective, 512 = 8*64)
    const int L = blockIdx.x;
    const int G = (L & 7) * 64 + (L >> 3);
    const int p = G & 15;            // pair index 0..15
    const int h = (G >> 4) & 15;     // head
    const int b = G >> 8;            // batch

    __shared__ alignas(16) unsigned char KsB[2][64 * 128];     // dbuf K, linear dest
    __shared__ alignas(16) unsigned char VtsB[2][64 * 128];    // dbuf V, linear dest
    __shared__ alignas(16) unsigned char PlsB[4 * 16 * 128];   // per-wave P

    const int tid  = threadIdx.x;
    const int lane = tid & 63, w = tid >> 6;
    const int fr   = lane & 15, kg = lane >> 4;
    unsigned char* PB = PlsB + w * 2048;

    const size_t baseQ = ((size_t)b * S) * D + (size_t)h * 64;
    const size_t baseV = ((size_t)b * D + (size_t)h * 64) * S;

    // pair (31-p, p): total key-tiles = (32-p) + (p+1) = 33, uniform
    attn_sweep(31 - p, qp, kp, vt, vtail, ctx, KsB, VtsB, PB,
               baseQ, baseV, b, h, lane, w, fr, kg);
    attn_sweep(p, qp, kp, vt, vtail, ctx, KsB, VtsB, PB,
               baseQ, baseV, b, h, lane, w, fr, kg);
}

// ---------------------------------------------------------------------------
extern "C" void kernel_launch(void* const* d_in, const int* in_sizes, int n_in,
                              void* d_out, int out_size, void* d_ws, size_t ws_size,
                              hipStream_t stream) {
    constexpr int B = 2, S = 2048, D = 1024;
    constexpr int M = B * S;                 // 4096
    constexpr size_t MD = (size_t)M * D;     // 4M elements

    const float* Q  = (const float*)d_in[0];
    const float* K  = (const float*)d_in[1];
    const float* V  = (const float*)d_in[2];
    const float* Wq = (const float*)d_in[4];
    const float* bq = (const float*)d_in[5];
    const float* Wk = (const float*)d_in[6];
    const float* bk = (const float*)d_in[7];
    const float* Wv = (const float*)d_in[8];
    const float* bv = (const float*)d_in[9];
    const float* Wo = (const float*)d_in[10];
    const float* bo = (const float*)d_in[11];

    // d_out (16 MiB, dead until final GEMM): qc (8 MiB) + kc (8 MiB)
    unsigned short* qc = (unsigned short*)d_out;
    unsigned short* kc = qc + MD;
    // d_ws (40 MiB): qb, kb, vtg, vc/ctx (8 MiB each) + Wto/Wtq/Wtk/Wtv (2 MiB each)
    char* ws = (char*)d_ws;
    unsigned short* qb  = (unsigned short*)(ws);
    unsigned short* kb  = (unsigned short*)(ws + (8u << 20));
    unsigned short* vtg = (unsigned short*)(ws + (16u << 20));
    unsigned short* vc  = (unsigned short*)(ws + (24u << 20));
    unsigned short* Wto = (unsigned short*)(ws + (32u << 20));
    unsigned short* Wtq = (unsigned short*)(ws + (34u << 20));
    unsigned short* Wtk = (unsigned short*)(ws + (36u << 20));
    unsigned short* Wtv = (unsigned short*)(ws + (38u << 20));
    unsigned short* ctx = vc;                       // aliases vc (dead by then)
    float* vtail        = (float*)Wtq;              // aliases Wtq (dead by then)

    dim3 blk(256);
    k_prep<<<dim3(4096), blk, 0, stream>>>(
        Q, K, V, qc, kc, vc, Wq, Wk, Wv, Wo, Wtq, Wtk, Wtv, Wto);
    k_gemm_bf16<1, 64><<<dim3(M / 128, D / 64, 3), blk, 0, stream>>>(
        qc, kc, vc, Wtq, Wtk, Wtv, bq, bk, bv, qb, kb, vtg);
    k_vtail<<<dim3((B * D) / 4), blk, 0, stream>>>(vtg, vtail);
    k_attn<<<dim3(512), blk, 0, stream>>>(qb, kb, vtg, vtail, ctx);
    k_gemm_bf16<0, 64><<<dim3(M / 128, D / 64, 1), blk, 0, stream>>>(
        ctx, ctx, ctx, Wto, Wto, Wto, bo, bo, bo, d_out, d_out, d_out);
}

// Round 21
// 115.417 us; speedup vs baseline: 1.1792x; 1.0203x over previous
//
#include <hip/hip_runtime.h>
#include <hip/hip_bf16.h>
#include <stdint.h>
#include <math.h>

#define DI __device__ __forceinline__

typedef __bf16 bf16x8 __attribute__((ext_vector_type(8)));
typedef float f32x4 __attribute__((ext_vector_type(4)));
typedef unsigned short ushortx8 __attribute__((ext_vector_type(8)));

// fp32 -> bf16 round-to-nearest-even (scalar path)
DI unsigned short f2bf(float f) {
    unsigned int u = __builtin_bit_cast(unsigned int, f);
    u += 0x7fffu + ((u >> 16) & 1u);
    return (unsigned short)(u >> 16);
}

// packed fp32x2 -> bf16x2 (1 VALU op). lo -> bits 0-15, hi -> bits 16-31.
DI unsigned int cvt_pk_bf16(float lo, float hi) {
    unsigned int r;
    asm("v_cvt_pk_bf16_f32 %0, %1, %2" : "=v"(r) : "v"(lo), "v"(hi));
    return r;
}

DI f32x4 mfma_16x16x32_bf16(bf16x8 a, bf16x8 b, f32x4 c) {
    return __builtin_amdgcn_mfma_f32_16x16x32_bf16(a, b, c, 0, 0, 0);
}

// async global->LDS, 16B per lane. LDS dest: wave-uniform base + lane*16.
DI void gload16(const unsigned short* g, unsigned short* l) {
    __builtin_amdgcn_global_load_lds(
        (const __attribute__((address_space(1))) void*)g,
        (__attribute__((address_space(3))) void*)l, 16, 0, 0);
}

// ---------------------------------------------------------------------------
// k_prep: fused prep (proven). Blocks 0..3071: fp32->bf16 cvt of Q/K/V.
// Blocks 3072..4095: W -> Wt bf16 transpose (4 matrices, 64x64 tiles).
// ---------------------------------------------------------------------------
__global__ __launch_bounds__(256) void k_prep(
    const float* __restrict__ Q, const float* __restrict__ K, const float* __restrict__ V,
    unsigned short* __restrict__ qc, unsigned short* __restrict__ kc, unsigned short* __restrict__ vc,
    const float* __restrict__ w0, const float* __restrict__ w1,
    const float* __restrict__ w2, const float* __restrict__ w3,
    unsigned short* __restrict__ o0, unsigned short* __restrict__ o1,
    unsigned short* __restrict__ o2, unsigned short* __restrict__ o3)
{
    constexpr int N = 1024;
    __shared__ unsigned short L[64 * 64];
    const int bx = blockIdx.x;
    const int tid = threadIdx.x;

    if (bx < 3072) {
        const int z = bx >> 10;
        const int ib = bx & 1023;
        const float* s = z == 0 ? Q : z == 1 ? K : V;
        unsigned short* d = z == 0 ? qc : z == 1 ? kc : vc;
        const int i0 = ib * 256 + tid;
        #pragma unroll
        for (int it = 0; it < 4; ++it) {
            const int i = i0 + it * 262144;
            const float4 v = reinterpret_cast<const float4*>(s)[i];
            uint2 pk;
            pk.x = cvt_pk_bf16(v.x, v.y);
            pk.y = cvt_pk_bf16(v.z, v.w);
            reinterpret_cast<uint2*>(d)[i] = pk;
        }
    } else {
        const int r4 = bx - 3072;
        const int z = r4 >> 8;
        const int tile = r4 & 255;
        const float* W = z == 0 ? w0 : z == 1 ? w1 : z == 2 ? w2 : w3;
        unsigned short* O = z == 0 ? o0 : z == 1 ? o1 : z == 2 ? o2 : o3;
        const int k0 = (tile >> 4) * 64, n0 = (tile & 15) * 64;

        const int r = tid >> 2, cbase = (tid & 3) * 16;
        #pragma unroll
        for (int i = 0; i < 4; ++i) {
            const int c = cbase + i * 4;
            const float4 v = *reinterpret_cast<const float4*>(&W[(size_t)(k0 + r) * N + n0 + c]);
            uint2 pk;
            pk.x = cvt_pk_bf16(v.x, v.y);
            pk.y = cvt_pk_bf16(v.z, v.w);
            const int byte = r * 128 + ((c * 2) ^ ((r & 7) << 4));
            *reinterpret_cast<uint2*>(reinterpret_cast<char*>(L) + byte) = pk;
        }
        __syncthreads();

        const int n = tid >> 2, kc2 = (tid & 3) * 16;
        ushortx8 v0, v1;
        #pragma unroll
        for (int j = 0; j < 8; ++j) {
            const int ka = kc2 + j, kb2 = kc2 + 8 + j;
            v0[j] = *reinterpret_cast<const unsigned short*>(
                reinterpret_cast<const char*>(L) + ka * 128 + ((n * 2) ^ ((ka & 7) << 4)));
            v1[j] = *reinterpret_cast<const unsigned short*>(
                reinterpret_cast<const char*>(L) + kb2 * 128 + ((n * 2) ^ ((kb2 & 7) << 4)));
        }
        unsigned short* op = &O[(size_t)(n0 + n) * N + k0 + kc2];
        *reinterpret_cast<ushortx8*>(op) = v0;
        *reinterpret_cast<ushortx8*>(op + 8) = v1;
    }
}

// ---------------------------------------------------------------------------
// bf16 GEMM, BK=64, both-sides swizzle (proven; conflicts = 0). BN=64 both.
// ---------------------------------------------------------------------------
template <int MODE, int BN>
__global__ __launch_bounds__(256) void k_gemm_bf16(
    const unsigned short* __restrict__ A0, const unsigned short* __restrict__ A1,
    const unsigned short* __restrict__ A2,
    const unsigned short* __restrict__ B0, const unsigned short* __restrict__ B1,
    const unsigned short* __restrict__ B2,
    const float* __restrict__ bias0, const float* __restrict__ bias1,
    const float* __restrict__ bias2,
    void* C0, void* C1, void* C2)
{
    constexpr int K = 1024, N = 1024;
    constexpr int NJ = BN / 32;          // wave-col fragments
    const int z = MODE ? blockIdx.z : 0;
    const unsigned short* A  = z == 0 ? A0 : z == 1 ? A1 : A2;
    const unsigned short* Bt = z == 0 ? B0 : z == 1 ? B1 : B2;
    const float* bias        = z == 0 ? bias0 : z == 1 ? bias1 : bias2;
    void* C                  = z == 0 ? C0 : z == 1 ? C1 : C2;

    __shared__ unsigned short As[128 * 64];      // [row][k] 128-B rows
    __shared__ unsigned short Bs[BN * 64];

    const int tid  = threadIdx.x;
    const int lane = tid & 63;
    const int w    = tid >> 6;
    const int wr   = w >> 1, wc = w & 1;
    const int fr   = lane & 15, kg = lane >> 4;
    const int m0   = blockIdx.x * 128, n0 = blockIdx.y * BN;

    const int srow8 = lane >> 3;                       // 0..7
    const int sswz  = ((lane & 7) ^ (lane >> 3)) * 8;  // pre-swizzled k-offset

    f32x4 acc[4][NJ] = {};

    for (int t = 0; t < K / 64; ++t) {
        const int k0 = t * 64;
        #pragma unroll
        for (int it = 0; it < 4; ++it) {
            const int c = w * 4 + it;
            gload16(&A[(size_t)(m0 + c * 8 + srow8) * K + k0 + sswz], &As[c * 512]);
            if (BN == 128)
                gload16(&Bt[(size_t)(n0 + c * 8 + srow8) * K + k0 + sswz], &Bs[c * 512]);
        }
        if (BN == 64) {
            #pragma unroll
            for (int it = 0; it < 2; ++it) {
                const int c = w * 2 + it;    // 8 chunks cover 64 rows
                gload16(&Bt[(size_t)(n0 + c * 8 + srow8) * K + k0 + sswz], &Bs[c * 512]);
            }
        }
        __syncthreads();

        const int rsw = (fr & 7) << 4;   // read-side XOR (byte)
        #pragma unroll
        for (int kh = 0; kh < 2; ++kh) {
            bf16x8 af[4], bfj[NJ];
            #pragma unroll
            for (int i = 0; i < 4; ++i)
                af[i] = *reinterpret_cast<const bf16x8*>(
                    reinterpret_cast<const char*>(As) +
                    (wr * 64 + i * 16 + fr) * 128 + ((kh * 64 + kg * 16) ^ rsw));
            #pragma unroll
            for (int j = 0; j < NJ; ++j)
                bfj[j] = *reinterpret_cast<const bf16x8*>(
                    reinterpret_cast<const char*>(Bs) +
                    (wc * (BN / 2) + j * 16 + fr) * 128 + ((kh * 64 + kg * 16) ^ rsw));
            #pragma unroll
            for (int i = 0; i < 4; ++i)
                #pragma unroll
                for (int j = 0; j < NJ; ++j)
                    acc[i][j] = mfma_16x16x32_bf16(af[i], bfj[j], acc[i][j]);
        }
        __syncthreads();
    }

    if (MODE == 1 && z == 2) {
        // V: store transposed per batch: vt[(bb*1024 + n)*2048 + s]
        unsigned short* vt = reinterpret_cast<unsigned short*>(C);
        #pragma unroll
        for (int i = 0; i < 4; ++i) {
            const int m = m0 + wr * 64 + i * 16 + kg * 4;
            const int bb = m >> 11, s = m & 2047;
            #pragma unroll
            for (int j = 0; j < NJ; ++j) {
                const int n = n0 + wc * (BN / 2) + j * 16 + fr;
                const float bv = bias[n];
                uint2 pk;
                pk.x = cvt_pk_bf16(acc[i][j][0] + bv, acc[i][j][1] + bv);
                pk.y = cvt_pk_bf16(acc[i][j][2] + bv, acc[i][j][3] + bv);
                *reinterpret_cast<uint2*>(&vt[((size_t)(bb * 1024 + n)) * 2048 + s]) = pk;
            }
        }
    } else if (MODE == 1) {
        // z==0 (Q): fold 1/sqrt(64) * log2(e) so attention uses native exp2.
        const float sc = (z == 0) ? 0.125f * 1.44269504088896340736f : 1.0f;
        unsigned short* Cb = reinterpret_cast<unsigned short*>(C);
        #pragma unroll
        for (int i = 0; i < 4; ++i) {
            const int m = m0 + wr * 64 + i * 16 + kg * 4;
            #pragma unroll
            for (int j = 0; j < NJ; ++j) {
                const int n = n0 + wc * (BN / 2) + j * 16 + fr;
                const float bv = bias[n];
                const unsigned int p0 = cvt_pk_bf16((acc[i][j][0] + bv) * sc, (acc[i][j][1] + bv) * sc);
                const unsigned int p1 = cvt_pk_bf16((acc[i][j][2] + bv) * sc, (acc[i][j][3] + bv) * sc);
                Cb[(size_t)(m + 0) * N + n] = (unsigned short)p0;
                Cb[(size_t)(m + 1) * N + n] = (unsigned short)(p0 >> 16);
                Cb[(size_t)(m + 2) * N + n] = (unsigned short)p1;
                Cb[(size_t)(m + 3) * N + n] = (unsigned short)(p1 >> 16);
            }
        }
    } else {
        float* Cf = reinterpret_cast<float*>(C);
        #pragma unroll
        for (int i = 0; i < 4; ++i) {
            const int m = m0 + wr * 64 + i * 16 + kg * 4;
            #pragma unroll
            for (int j = 0; j < NJ; ++j) {
                const int n = n0 + wc * (BN / 2) + j * 16 + fr;
                const float bv = bias[n];
                #pragma unroll
                for (int r = 0; r < 4; ++r)
                    Cf[(size_t)(m + r) * N + n] = acc[i][j][r] + bv;
            }
        }
    }
}

// ---------------------------------------------------------------------------
// V tail suffix sums (unchanged).
// ---------------------------------------------------------------------------
__global__ __launch_bounds__(256) void k_vtail(
    const unsigned short* __restrict__ vt, float* __restrict__ vtail)
{
    const int row = blockIdx.x * 4 + (threadIdx.x >> 6);
    const int l = threadIdx.x & 63;
    const unsigned short* p = &vt[(size_t)row * 2048 + l * 32];
    float s = 0.f;
    #pragma unroll
    for (int i = 0; i < 4; ++i) {
        ushortx8 v = *reinterpret_cast<const ushortx8*>(&p[i * 8]);
        #pragma unroll
        for (int e = 0; e < 8; ++e)
            s += __builtin_bit_cast(float, (unsigned int)v[e] << 16);
    }
    #pragma unroll
    for (int off = 1; off < 64; off <<= 1) {
        const float t = __shfl_down(s, off, 64);
        s += (l + off < 64) ? t : 0.f;
    }
    float tv = __shfl(s, (2 * l + 2) & 63, 64);
    if (l == 31) tv = 0.f;
    if (l < 32) vtail[(size_t)row * 32 + l] = tv;
}

// ---------------------------------------------------------------------------
// Attention v11 = v10 + T3/T4 counted-vmcnt pipeline: 3 LDS buffers, DMA for
// tile t+2 issued while computing t, per-thread s_waitcnt vmcnt(4) (tile
// t+1's 4 loads landed; t+2's stay in flight) + RAW s_barrier -- the drain
// never goes to 0 in the main loop (m201/m218 pattern). Buffer-reuse safety:
// the barrier at end of iter t guarantees all waves consumed buf[t%3] before
// iter t+1 issues DMA(t+3) into it... (t+3)%3 == t%3. End-of-sweep full
// __syncthreads gives a clean slate before the next sweep reuses buffers.
// ---------------------------------------------------------------------------
template <bool MASK>
DI void attn_tile(const unsigned char* KsB, const unsigned char* VtsB,
                  unsigned char* PB, bf16x8 qf0, bf16x8 qf1,
                  f32x4 (&o)[4], f32x4& oS, int w, int fr, int kg)
{
    const int sw = (fr & 7) << 4;
    #pragma unroll
    for (int j = 0; j < 4; ++j) {
        const int row = j * 16 + fr;
        const bf16x8 kf0 = *reinterpret_cast<const bf16x8*>(KsB + row * 128 + ((kg * 16) ^ sw));
        const bf16x8 kf1 = *reinterpret_cast<const bf16x8*>(KsB + row * 128 + ((64 + kg * 16) ^ sw));
        f32x4 s = {0.f, 0.f, 0.f, 0.f};
        __builtin_amdgcn_s_setprio(1);
        s = mfma_16x16x32_bf16(kf0, qf0, s);   // swapped: A=K rows (keys), B=Q
        s = mfma_16x16x32_bf16(kf1, qf1, s);
        __builtin_amdgcn_s_setprio(0);
        float p[4];
        #pragma unroll
        for (int r = 0; r < 4; ++r) {
            float e = __builtin_amdgcn_exp2f(s[r]);   // q pre-scaled by log2e
            if (MASK && (j * 16 + kg * 4 + r > w * 16 + fr)) e = 1.0f;  // exp(-1e-8)==1.0f
            p[r] = e;
        }
        uint2 pk;
        pk.x = cvt_pk_bf16(p[0], p[1]);
        pk.y = cvt_pk_bf16(p[2], p[3]);
        *reinterpret_cast<uint2*>(PB + fr * 128 + ((j * 32 + kg * 8) ^ sw)) = pk;
    }
    // all-ones B fragment (bf16 1.0 broadcast) for the P row-sum MFMA
    bf16x8 ones;
    #pragma unroll
    for (int b = 0; b < 8; ++b) ones[b] = (__bf16)1.0f;
    __builtin_amdgcn_s_setprio(1);
    #pragma unroll
    for (int kk = 0; kk < 2; ++kk) {
        const bf16x8 pf = *reinterpret_cast<const bf16x8*>(PB + fr * 128 + ((kk * 64 + kg * 16) ^ sw));
        #pragma unroll
        for (int n = 0; n < 4; ++n) {
            const int vrow = n * 16 + fr;
            const bf16x8 vf = *reinterpret_cast<const bf16x8*>(VtsB + vrow * 128 + ((kk * 64 + kg * 16) ^ sw));
            o[n] = mfma_16x16x32_bf16(pf, vf, o[n]);
        }
        oS = mfma_16x16x32_bf16(pf, ones, oS);   // denominator via matrix pipe
    }
    __builtin_amdgcn_s_setprio(0);
}

DI void attn_sweep(int qt,
                   const unsigned short* __restrict__ qp,
                   const unsigned short* __restrict__ kp,
                   const unsigned short* __restrict__ vt,
                   const float* __restrict__ vtail,
                   unsigned short* __restrict__ ctx,
                   unsigned char (*KsB)[64 * 128], unsigned char (*VtsB)[64 * 128],
                   unsigned char* PB, size_t baseQ, size_t baseV, int b, int h,
                   int lane, int w, int fr, int kg)
{
    constexpr int S = 2048, D = 1024;
    const int q0 = qt * 64 + w * 16;

    bf16x8 qf0, qf1;
    {
        const size_t roff = baseQ + (size_t)(q0 + fr) * D;
        qf0 = *reinterpret_cast<const bf16x8*>(&qp[roff + kg * 8]);
        qf1 = *reinterpret_cast<const bf16x8*>(&qp[roff + 32 + kg * 8]);
    }

    f32x4 o[4] = {};
    f32x4 oS = {};
    const int NT = qt + 1;

    // staging: 8 chunks of 1 KB (8 rows x 128 B); wave w owns chunks {2w,2w+1};
    // lane covers row c*8+(lane>>3) at pre-swizzled col (4 loads/thread/tile).
    const int srow = lane >> 3;
    const int sswz = ((lane & 7) ^ srow) * 8;
    const int c0   = w * 2;

    // DMA issue helper pattern (4 loads, fixed order: K(c0),V(c0),K(c1),V(c1))
    #define STAGE_DMA(TT, BUF)                                                   \
        {                                                                        \
            const int kb_ = (TT) * 64;                                           \
            _Pragma("unroll")                                                    \
            for (int i_ = 0; i_ < 2; ++i_) {                                     \
                const int c_ = c0 + i_;                                          \
                const int row_ = c_ * 8 + srow;                                  \
                gload16(&kp[baseQ + (size_t)(kb_ + row_) * D + sswz],            \
                        reinterpret_cast<unsigned short*>(KsB[BUF] + c_ * 1024));\
                gload16(&vt[baseV + (size_t)row_ * S + kb_ + sswz],              \
                        reinterpret_cast<unsigned short*>(VtsB[BUF] + c_ * 1024));\
            }                                                                    \
        }

    // prologue: tiles 0 and 1 in flight; wait tile 0 only (vmcnt counts both
    // outstanding groups; 4 left in flight = tile 1's).
    STAGE_DMA(0, 0);
    if (NT > 1) {
        STAGE_DMA(1, 1);
        asm volatile("s_waitcnt vmcnt(4)" ::: "memory");
    } else {
        asm volatile("s_waitcnt vmcnt(0)" ::: "memory");
    }
    __builtin_amdgcn_s_barrier();

    for (int t = 0; t < NT; ++t) {
        const int cur = t % 3;
        const bool has2 = (t + 2 < NT);
        if (has2) STAGE_DMA(t + 2, (t + 2) % 3);
        if (t == NT - 1)
            attn_tile<true>(KsB[cur], VtsB[cur], PB, qf0, qf1, o, oS, w, fr, kg);
        else
            attn_tile<false>(KsB[cur], VtsB[cur], PB, qf0, qf1, o, oS, w, fr, kg);
        if (t + 1 < NT) {
            // wait tile t+1's 4 loads (t+2's stay in flight), then raw barrier:
            // all waves have t+1 resident AND have finished reading buf[cur].
            if (has2) asm volatile("s_waitcnt vmcnt(4)" ::: "memory");
            else      asm volatile("s_waitcnt vmcnt(0)" ::: "memory");
            __builtin_amdgcn_s_barrier();
        }
    }
    #undef STAGE_DMA

    // denominator: oS[r] holds q-row (q0 + kg*4 + r)'s P-sum; add tail count.
    const float tailc = (float)(S - (qt + 1) * 64);
    float rlq[4];
    #pragma unroll
    for (int r = 0; r < 4; ++r) rlq[r] = 1.0f / (oS[r] + tailc);

    float tl[4];
    #pragma unroll
    for (int n = 0; n < 4; ++n)
        tl[n] = vtail[((size_t)(b * 1024) + h * 64 + n * 16 + fr) * 32 + qt];

    #pragma unroll
    for (int n = 0; n < 4; ++n)
        #pragma unroll
        for (int r = 0; r < 4; ++r) {
            const int qrow = q0 + kg * 4 + r;
            ctx[baseQ + (size_t)qrow * D + n * 16 + fr] = f2bf((o[n][r] + tl[n]) * rlq[r]);
        }

    // clean slate before the next sweep reuses the buffers (full drain)
    __syncthreads();
}

__global__ __launch_bounds__(256, 2) void k_attn(
    const unsigned short* __restrict__ qp,
    const unsigned short* __restrict__ kp,
    const unsigned short* __restrict__ vt,
    const float* __restrict__ vtail,
    unsigned short* __restrict__ ctx)
{
    constexpr int S = 2048, D = 1024;
    // T1 chunked XCD swizzle: G = (L%8)*64 + L/8 (bijective, 512 = 8*64)
    const int L = blockIdx.x;
    const int G = (L & 7) * 64 + (L >> 3);
    const int p = G & 15;            // pair index 0..15
    const int h = (G >> 4) & 15;     // head
    const int b = G >> 8;            // batch

    __shared__ alignas(16) unsigned char KsB[3][64 * 128];     // 3-buf K, linear dest
    __shared__ alignas(16) unsigned char VtsB[3][64 * 128];    // 3-buf V, linear dest
    __shared__ alignas(16) unsigned char PlsB[4 * 16 * 128];   // per-wave P

    const int tid  = threadIdx.x;
    const int lane = tid & 63, w = tid >> 6;
    const int fr   = lane & 15, kg = lane >> 4;
    unsigned char* PB = PlsB + w * 2048;

    const size_t baseQ = ((size_t)b * S) * D + (size_t)h * 64;
    const size_t baseV = ((size_t)b * D + (size_t)h * 64) * S;

    // pair (31-p, p): total key-tiles = (32-p) + (p+1) = 33, uniform
    attn_sweep(31 - p, qp, kp, vt, vtail, ctx, KsB, VtsB, PB,
               baseQ, baseV, b, h, lane, w, fr, kg);
    attn_sweep(p, qp, kp, vt, vtail, ctx, KsB, VtsB, PB,
               baseQ, baseV, b, h, lane, w, fr, kg);
}

// ---------------------------------------------------------------------------
extern "C" void kernel_launch(void* const* d_in, const int* in_sizes, int n_in,
                              void* d_out, int out_size, void* d_ws, size_t ws_size,
                              hipStream_t stream) {
    constexpr int B = 2, S = 2048, D = 1024;
    constexpr int M = B * S;                 // 4096
    constexpr size_t MD = (size_t)M * D;     // 4M elements

    const float* Q  = (const float*)d_in[0];
    const float* K  = (const float*)d_in[1];
    const float* V  = (const float*)d_in[2];
    const float* Wq = (const float*)d_in[4];
    const float* bq = (const float*)d_in[5];
    const float* Wk = (const float*)d_in[6];
    const float* bk = (const float*)d_in[7];
    const float* Wv = (const float*)d_in[8];
    const float* bv = (const float*)d_in[9];
    const float* Wo = (const float*)d_in[10];
    const float* bo = (const float*)d_in[11];

    // d_out (16 MiB, dead until final GEMM): qc (8 MiB) + kc (8 MiB)
    unsigned short* qc = (unsigned short*)d_out;
    unsigned short* kc = qc + MD;
    // d_ws (40 MiB): qb, kb, vtg, vc/ctx (8 MiB each) + Wto/Wtq/Wtk/Wtv (2 MiB each)
    char* ws = (char*)d_ws;
    unsigned short* qb  = (unsigned short*)(ws);
    unsigned short* kb  = (unsigned short*)(ws + (8u << 20));
    unsigned short* vtg = (unsigned short*)(ws + (16u << 20));
    unsigned short* vc  = (unsigned short*)(ws + (24u << 20));
    unsigned short* Wto = (unsigned short*)(ws + (32u << 20));
    unsigned short* Wtq = (unsigned short*)(ws + (34u << 20));
    unsigned short* Wtk = (unsigned short*)(ws + (36u << 20));
    unsigned short* Wtv = (unsigned short*)(ws + (38u << 20));
    unsigned short* ctx = vc;                       // aliases vc (dead by then)
    float* vtail        = (float*)Wtq;              // aliases Wtq (dead by then)

    dim3 blk(256);
    k_prep<<<dim3(4096), blk, 0, stream>>>(
        Q, K, V, qc, kc, vc, Wq, Wk, Wv, Wo, Wtq, Wtk, Wtv, Wto);
    k_gemm_bf16<1, 64><<<dim3(M / 128, D / 64, 3), blk, 0, stream>>>(
        qc, kc, vc, Wtq, Wtk, Wtv, bq, bk, bv, qb, kb, vtg);
    k_vtail<<<dim3((B * D) / 4), blk, 0, stream>>>(vtg, vtail);
    k_attn<<<dim3(512), blk, 0, stream>>>(qb, kb, vtg, vtail, ctx);
    k_gemm_bf16<0, 64><<<dim3(M / 128, D / 64, 1), blk, 0, stream>>>(
        ctx, ctx, ctx, Wto, Wto, Wto, bo, bo, bo, d_out, d_out, d_out);
}